// Round 11
// baseline (1682.954 us; speedup 1.0000x reference)
//
#include <hip/hip_runtime.h>

#define NGRAPH 512
#define NNODE  128
#define NEDGE  512
#define EMB    300
#define NLAYER 5
#define FA     9
#define FB     3
#define VV     64
#define KPAD   136   // padded K stride (bf16 elems) for A / xT tiles

typedef __bf16 bf16x8 __attribute__((ext_vector_type(8)));
typedef __bf16 bf16x4 __attribute__((ext_vector_type(4)));
typedef float  f32x4  __attribute__((ext_vector_type(4)));

__device__ __forceinline__ void gload_lds16(const void* gptr, void* lptr) {
    __builtin_amdgcn_global_load_lds(
        (const __attribute__((address_space(1))) void*)gptr,
        (__attribute__((address_space(3))) void*)lptr, 16, 0, 0);
}

// ---------------------------------------------------------------------------
// Kernel 0: weight prep — transpose w1/w2 to bf16 [N][K] (padded, zeros).
// w1t: [L][640][320] (real 600x300). w2t: [L][384][640] (real 300x600).
// ---------------------------------------------------------------------------
__global__ __launch_bounds__(256)
void prep_w_kernel(const float* __restrict__ w1, const float* __restrict__ w2,
                   __bf16* __restrict__ w1t, __bf16* __restrict__ w2t)
{
    const int i = blockIdx.x * 256 + threadIdx.x;
    const int T1 = NLAYER * 640 * 320;
    const int T2 = NLAYER * 384 * 640;
    if (i < T1) {
        const int l = i / (640 * 320);
        const int r = i - l * 640 * 320;
        const int n = r / 320, k = r - n * 320;
        float v = (n < 600 && k < 300) ? w1[((size_t)l * 300 + k) * 600 + n] : 0.f;
        w1t[i] = (__bf16)v;
    } else if (i < T1 + T2) {
        const int j = i - T1;
        const int l = j / (384 * 640);
        const int r = j - l * 384 * 640;
        const int n = r / 640, k = r - n * 640;
        float v = (n < 300 && k < 600) ? w2[((size_t)l * 600 + k) * 300 + n] : 0.f;
        w2t[j] = (__bf16)v;
    }
}

// ---------------------------------------------------------------------------
// Kernel 1a: adjacency build (unchanged)
// ---------------------------------------------------------------------------
__global__ __launch_bounds__(512)
void adj_kernel(const int* __restrict__ edge_index,
                const int* __restrict__ edge_attr,
                const float* __restrict__ bond_tab_root,
                const float* __restrict__ edge_lin_w,
                const float* __restrict__ edge_lin_b,
                __bf16* __restrict__ Ahi_g, __bf16* __restrict__ Alo_g)
{
    __shared__ float A[128 * 129];
    __shared__ float ew_s[NEDGE];
    __shared__ int   es[NEDGE];
    __shared__ float rinv[128];
    __shared__ float cinv[128];

    const int tid = threadIdx.x;
    const int g   = blockIdx.x;
    int* Ai = (int*)A;

    for (int e = tid; e < NEDGE; e += 512) {
        int r = edge_index[(g * 2 + 0) * NEDGE + e];
        int c = edge_index[(g * 2 + 1) * NEDGE + e];
        es[e] = r | (c << 8);
    }
    for (int i = tid; i < 128 * 129; i += 512) Ai[i] = -1;
    __syncthreads();

    {
        const int wave = tid >> 6, lane = tid & 63;
        const float elb = edge_lin_b[0];
        for (int e = wave * 64; e < wave * 64 + 64; ++e) {
            const int base = (g * NEDGE + e) * 3;
            const int a0 = edge_attr[base + 0];
            const int a1 = edge_attr[base + 1];
            const int a2 = edge_attr[base + 2];
            const float* t0 = bond_tab_root + (0 * VV + a0) * EMB;
            const float* t1 = bond_tab_root + (1 * VV + a1) * EMB;
            const float* t2 = bond_tab_root + (2 * VV + a2) * EMB;
            float acc = 0.f;
            for (int d = lane; d < EMB; d += 64)
                acc += (t0[d] + t1[d] + t2[d]) * edge_lin_w[d];
            #pragma unroll
            for (int off = 32; off > 0; off >>= 1) acc += __shfl_xor(acc, off, 64);
            if (lane == 0) ew_s[e] = 1.f / (1.f + expf(-(acc + elb)));
        }
    }
    for (int e = tid; e < NEDGE; e += 512) {
        int r = es[e] & 255, c = es[e] >> 8;
        atomicMax(&Ai[r * 129 + c], e);
        atomicMax(&Ai[c * 129 + r], 512 + e);
    }
    __syncthreads();
    for (int i = tid; i < 128 * 129; i += 512) {
        int p = Ai[i];
        A[i] = (p < 0) ? 0.f : ew_s[p & 511];
    }
    __syncthreads();
    if (tid < 128) A[tid * 129 + tid] += 1.f;
    __syncthreads();
    if (tid < 128) {
        float rs = 0.f, cs = 0.f;
        for (int j = 0; j < 128; ++j) { rs += A[tid * 129 + j]; cs += A[j * 129 + tid]; }
        rinv[tid] = 1.f / sqrtf(rs);
        cinv[tid] = 1.f / sqrtf(cs);
    }
    __syncthreads();
    for (int i = tid; i < 128 * KPAD; i += 512) {
        const int m = i / KPAD, k = i - m * KPAD;
        float v = (k < 128) ? A[m * 129 + k] * cinv[m] * rinv[k] : 0.f;
        __bf16 hi = (__bf16)v;
        Ahi_g[(size_t)g * 128 * KPAD + i] = hi;
        Alo_g[(size_t)g * 128 * KPAD + i] = (__bf16)(v - (float)hi);
    }
}

// ---------------------------------------------------------------------------
// Kernel 1b: diffusion via MFMA with split-bf16 (unchanged)
// ---------------------------------------------------------------------------
__global__ __launch_bounds__(512)
void diffuse_mm_kernel(const int* __restrict__ order_p,
                       const int* __restrict__ x_atom,
                       const float* __restrict__ atom_tab,
                       const __bf16* __restrict__ Ahi_g,
                       const __bf16* __restrict__ Alo_g,
                       float* __restrict__ h)
{
    __shared__ __bf16 Ahi[128 * KPAD];
    __shared__ __bf16 Alo[128 * KPAD];
    __shared__ __bf16 xt[4 * 64 * KPAD];
    __shared__ int    xat[128 * FA];

    const int tid  = threadIdx.x;
    const int g    = blockIdx.x;
    const int lane = tid & 63;
    const int wid  = tid >> 6;
    const int wm   = (wid >> 1) * 32;
    const int wn   = (wid & 1) * 32;
    const int lr   = lane & 15;
    const int q4   = (lane >> 4) * 4;
    const int kc   = (lane >> 4) * 8;

    for (int idx = tid; idx < 128 * KPAD / 8; idx += 512) {
        gload_lds16(Ahi_g + (size_t)g * 128 * KPAD + idx * 8, (char*)Ahi + idx * 16);
        gload_lds16(Alo_g + (size_t)g * 128 * KPAD + idx * 8, (char*)Alo + idx * 16);
    }
    for (int i = tid; i < 128 * FA; i += 512) xat[i] = x_atom[g * 128 * FA + i];
    __syncthreads();

    const int   ord    = order_p[0];
    const float yscale = 1.f / (float)(ord + 1);

    for (int cb = 0; cb < 5; ++cb) {
        const int dbase = cb * 64;

        float yacc[2][2][4];
        #pragma unroll
        for (int mi = 0; mi < 2; ++mi) {
            #pragma unroll
            for (int ni = 0; ni < 2; ++ni) {
                const int n_ = wn + ni * 16 + lr;
                const int d  = dbase + n_;
                #pragma unroll
                for (int r = 0; r < 4; ++r) {
                    const int m_ = wm + mi * 16 + q4 + r;
                    float v = 0.f;
                    if (d < EMB) {
                        #pragma unroll
                        for (int f = 0; f < FA; ++f)
                            v += atom_tab[(size_t)((f << 6) + xat[m_ * FA + f]) * EMB + d];
                        v *= 0.8f;
                    }
                    yacc[mi][ni][r] = v;
                    __bf16 hi = (__bf16)v;
                    xt[0 * 64 * KPAD + n_ * KPAD + m_] = hi;
                    xt[1 * 64 * KPAD + n_ * KPAD + m_] = (__bf16)(v - (float)hi);
                }
            }
        }
        __syncthreads();

        int curbuf = 0;
        for (int o = 0; o < ord; ++o) {
            const __bf16* xh = xt + (curbuf * 2 + 0) * 64 * KPAD;
            const __bf16* xl = xt + (curbuf * 2 + 1) * 64 * KPAD;
            f32x4 racc[2][2];
            #pragma unroll
            for (int mi = 0; mi < 2; ++mi)
                #pragma unroll
                for (int ni = 0; ni < 2; ++ni) racc[mi][ni] = (f32x4){0.f, 0.f, 0.f, 0.f};

            #pragma unroll
            for (int ks = 0; ks < 4; ++ks) {
                const int k0 = ks * 32 + kc;
                bf16x8 ah[2], al[2], bh[2], bl[2];
                #pragma unroll
                for (int mi = 0; mi < 2; ++mi) {
                    ah[mi] = *(const bf16x8*)&Ahi[(wm + mi * 16 + lr) * KPAD + k0];
                    al[mi] = *(const bf16x8*)&Alo[(wm + mi * 16 + lr) * KPAD + k0];
                }
                #pragma unroll
                for (int ni = 0; ni < 2; ++ni) {
                    bh[ni] = *(const bf16x8*)&xh[(wn + ni * 16 + lr) * KPAD + k0];
                    bl[ni] = *(const bf16x8*)&xl[(wn + ni * 16 + lr) * KPAD + k0];
                }
                #pragma unroll
                for (int mi = 0; mi < 2; ++mi) {
                    #pragma unroll
                    for (int ni = 0; ni < 2; ++ni) {
                        racc[mi][ni] = __builtin_amdgcn_mfma_f32_16x16x32_bf16(
                            ah[mi], bh[ni], racc[mi][ni], 0, 0, 0);
                        racc[mi][ni] = __builtin_amdgcn_mfma_f32_16x16x32_bf16(
                            ah[mi], bl[ni], racc[mi][ni], 0, 0, 0);
                        racc[mi][ni] = __builtin_amdgcn_mfma_f32_16x16x32_bf16(
                            al[mi], bh[ni], racc[mi][ni], 0, 0, 0);
                    }
                }
            }

            __bf16* nh = xt + ((curbuf ^ 1) * 2 + 0) * 64 * KPAD;
            __bf16* nl = xt + ((curbuf ^ 1) * 2 + 1) * 64 * KPAD;
            #pragma unroll
            for (int mi = 0; mi < 2; ++mi) {
                #pragma unroll
                for (int ni = 0; ni < 2; ++ni) {
                    const int n_ = wn + ni * 16 + lr;
                    const int mbase = wm + mi * 16 + q4;
                    bf16x4 hv, lv;
                    #pragma unroll
                    for (int r = 0; r < 4; ++r) {
                        const float v = racc[mi][ni][r];
                        yacc[mi][ni][r] += v;
                        __bf16 hi = (__bf16)v;
                        hv[r] = hi;
                        lv[r] = (__bf16)(v - (float)hi);
                    }
                    *(bf16x4*)&nh[n_ * KPAD + mbase] = hv;
                    *(bf16x4*)&nl[n_ * KPAD + mbase] = lv;
                }
            }
            __syncthreads();
            curbuf ^= 1;
        }

        #pragma unroll
        for (int mi = 0; mi < 2; ++mi) {
            #pragma unroll
            for (int ni = 0; ni < 2; ++ni) {
                const int n_ = wn + ni * 16 + lr;
                const int d  = dbase + n_;
                if (d < EMB) {
                    #pragma unroll
                    for (int r = 0; r < 4; ++r) {
                        const int m_ = wm + mi * 16 + q4 + r;
                        h[(size_t)(g * 128 + m_) * EMB + d] = yacc[mi][ni][r] * yscale;
                    }
                }
            }
        }
    }
}

// ---------------------------------------------------------------------------
// Kernel 2: GIN aggregation, CSR gather, 2 blocks/graph (unchanged from r9).
// ---------------------------------------------------------------------------
__global__ __launch_bounds__(1024)
void agg_kernel(const int* __restrict__ edge_index,
                const int* __restrict__ edge_attr,
                const float* __restrict__ bond_tabs,
                const float* __restrict__ eps_all,
                const int l,
                const float* __restrict__ h,
                __bf16* __restrict__ zb)
{
    __shared__ __bf16         hs[128 * 160];
    __shared__ int            epk[NEDGE];
    __shared__ unsigned short eord[NEDGE];
    __shared__ int            cnt[128];
    __shared__ int            off_[129];
    __shared__ int            fill[128];

    const int tid  = threadIdx.x;
    const int g    = blockIdx.x >> 1;
    const int coff = (blockIdx.x & 1) * 160;
    const int wave = tid >> 6, lane = tid & 63;
    const float epl = 1.f + eps_all[l];
    const float* bt = bond_tabs + (size_t)l * FB * VV * EMB;

    if (tid < 128) { cnt[tid] = 0; fill[tid] = 0; }
    __syncthreads();
    if (tid < NEDGE) {
        const int s_ = edge_index[(g * 2 + 0) * NEDGE + tid];
        const int d_ = edge_index[(g * 2 + 1) * NEDGE + tid];
        const int base = (g * NEDGE + tid) * 3;
        epk[tid] = s_ | (d_ << 7) | (edge_attr[base + 0] << 14)
                 | (edge_attr[base + 1] << 20) | (edge_attr[base + 2] << 26);
        atomicAdd(&cnt[d_], 1);
    }
    for (int idx = tid; idx < 128 * 40; idx += 1024) {
        const int r = idx / 40, q = (idx - r * 40) * 4;
        bf16x4 v;
        #pragma unroll
        for (int j = 0; j < 4; ++j) {
            const int d = coff + q + j;
            v[j] = (__bf16)((d < EMB) ? h[(size_t)(g * 128 + r) * EMB + d] : 0.f);
        }
        *(bf16x4*)&hs[r * 160 + q] = v;
    }
    __syncthreads();
    if (tid < 64) {
        const int a = cnt[tid];
        const int b = cnt[64 + tid];
        int ia = a;
        #pragma unroll
        for (int o = 1; o < 64; o <<= 1) {
            int t = __shfl_up(ia, o, 64);
            if (tid >= o) ia += t;
        }
        const int totA = __shfl(ia, 63, 64);
        int ib = b;
        #pragma unroll
        for (int o = 1; o < 64; o <<= 1) {
            int t = __shfl_up(ib, o, 64);
            if (tid >= o) ib += t;
        }
        off_[tid]      = ia - a;
        off_[64 + tid] = totA + ib - b;
        if (tid == 63) off_[128] = totA + ib;
    }
    __syncthreads();
    if (tid < NEDGE) {
        const int d_ = (epk[tid] >> 7) & 127;
        const int pos = off_[d_] + atomicAdd(&fill[d_], 1);
        eord[pos] = (unsigned short)tid;
    }
    __syncthreads();

    const int d0 = lane, d1 = lane + 64, d2 = lane + 128;
    const bool r0 = (coff + d0) < EMB;
    const bool r1 = (coff + d1) < EMB;
    const bool r2 = (d2 < 160) && ((coff + d2) < EMB);

    for (int n = wave; n < 128; n += 16) {
        const float* hrow = h + (size_t)(g * 128 + n) * EMB + coff;
        float a0 = r0 ? epl * hrow[d0] : 0.f;
        float a1 = r1 ? epl * hrow[d1] : 0.f;
        float a2 = r2 ? epl * hrow[d2] : 0.f;
        const int eEnd = off_[n + 1];
        for (int ee = off_[n]; ee < eEnd; ++ee) {
            const int p   = epk[eord[ee]];
            const int src = p & 127;
            const float* t0 = bt + ((p >> 14) & 63) * EMB + coff;
            const float* t1 = bt + (64  + ((p >> 20) & 63)) * EMB + coff;
            const float* t2 = bt + (128 + ((p >> 26) & 63)) * EMB + coff;
            if (r0) a0 += fmaxf((float)hs[src * 160 + d0] + t0[d0] + t1[d0] + t2[d0], 0.f);
            if (r1) a1 += fmaxf((float)hs[src * 160 + d1] + t0[d1] + t1[d1] + t2[d1], 0.f);
            if (r2) a2 += fmaxf((float)hs[src * 160 + d2] + t0[d2] + t1[d2] + t2[d2], 0.f);
        }
        __bf16* zrow = zb + (size_t)(g * 128 + n) * 320 + coff;
        zrow[d0] = (__bf16)a0;
        zrow[d1] = (__bf16)a1;
        if (d2 < 160) zrow[d2] = (__bf16)a2;
    }
}

// ---------------------------------------------------------------------------
// Kernel 3: FUSED MLP — z1 never touches HBM.
// Block = 32 M-rows, 512 thr (8 waves), 62.5 KB LDS -> 2 blocks/CU.
//  phase 1: zs[32][640]bf16 = relu(bn1(zbs @ w1t^T)); wave w owns 80 cols.
//  phase 2: h[32][300]fp32 = bn(zs @ w2t^T) (+relu unless last); wave w
//           owns 48 cols (8x48=384 = w2t N-pad), stores masked n<300.
// B-fragments read directly from L2-resident w1t/w2t (no LDS staging).
// ---------------------------------------------------------------------------
template <int RELU>
__global__ __launch_bounds__(512)
void mlp_kernel(const __bf16* __restrict__ zb,
                const __bf16* __restrict__ w1t_l,   // [640][320]
                const __bf16* __restrict__ w2t_l,   // [384][640]
                float* __restrict__ h,
                const float* __restrict__ b1_l, const float* __restrict__ g1_l,
                const float* __restrict__ e1_l,
                const float* __restrict__ b2_l, const float* __restrict__ g2_l,
                const float* __restrict__ e2_l)
{
    __shared__ __bf16 zbs[32 * 328];   // 20,992 B  (A operand, padded stride)
    __shared__ __bf16 zs[32 * 648];    // 41,472 B  (intermediate z, padded)

    const int tid  = threadIdx.x;
    const int bm   = blockIdx.x * 32;
    const int wave = tid >> 6, lane = tid & 63;
    const int lr   = lane & 15;
    const int kc   = (lane >> 4) * 8;
    const int q4   = (lane >> 4) * 4;

    // stage zb tile 32x320 -> padded LDS (reg-staged; 2.5 bf16x8 per thread)
    for (int idx = tid; idx < 32 * 40; idx += 512) {
        const int r = idx / 40, c = idx - r * 40;
        bf16x8 v = *(const bf16x8*)&zb[(size_t)(bm + r) * 320 + c * 8];
        *(bf16x8*)&zbs[r * 328 + c * 8] = v;
    }
    __syncthreads();

    // ---- phase 1: zs = relu(bn1(zbs @ w1)) ----
    {
        const int ncol0 = wave * 80;
        f32x4 acc[2][5];
        #pragma unroll
        for (int mi = 0; mi < 2; ++mi)
            #pragma unroll
            for (int ni = 0; ni < 5; ++ni) acc[mi][ni] = (f32x4){0.f, 0.f, 0.f, 0.f};

        #pragma unroll 2
        for (int kt = 0; kt < 10; ++kt) {
            const int k0 = kt * 32 + kc;
            bf16x8 a[2], b[5];
            #pragma unroll
            for (int mi = 0; mi < 2; ++mi)
                a[mi] = *(const bf16x8*)&zbs[(mi * 16 + lr) * 328 + k0];
            #pragma unroll
            for (int ni = 0; ni < 5; ++ni)
                b[ni] = *(const bf16x8*)&w1t_l[(size_t)(ncol0 + ni * 16 + lr) * 320 + k0];
            #pragma unroll
            for (int mi = 0; mi < 2; ++mi)
                #pragma unroll
                for (int ni = 0; ni < 5; ++ni)
                    acc[mi][ni] = __builtin_amdgcn_mfma_f32_16x16x32_bf16(
                        a[mi], b[ni], acc[mi][ni], 0, 0, 0);
        }
        #pragma unroll
        for (int ni = 0; ni < 5; ++ni) {
            const int n = ncol0 + ni * 16 + lr;
            const bool nv = (n < 600);
            const float gv = nv ? g1_l[n] : 0.f;
            const float bv = nv ? b1_l[n] : 0.f;
            const float ev = nv ? e1_l[n] : 0.f;
            #pragma unroll
            for (int mi = 0; mi < 2; ++mi) {
                #pragma unroll
                for (int r = 0; r < 4; ++r) {
                    const int m = mi * 16 + q4 + r;
                    float v = gv * (acc[mi][ni][r] + bv) + ev;
                    v = fmaxf(v, 0.f);
                    zs[m * 648 + n] = (__bf16)v;   // pad cols naturally 0
                }
            }
        }
    }
    __syncthreads();

    // ---- phase 2: h = bn(zs @ w2) (+relu unless last layer) ----
    {
        const int ncol0 = wave * 48;
        f32x4 acc[2][3];
        #pragma unroll
        for (int mi = 0; mi < 2; ++mi)
            #pragma unroll
            for (int ni = 0; ni < 3; ++ni) acc[mi][ni] = (f32x4){0.f, 0.f, 0.f, 0.f};

        #pragma unroll 2
        for (int kt = 0; kt < 20; ++kt) {
            const int k0 = kt * 32 + kc;
            bf16x8 a[2], b[3];
            #pragma unroll
            for (int mi = 0; mi < 2; ++mi)
                a[mi] = *(const bf16x8*)&zs[(mi * 16 + lr) * 648 + k0];
            #pragma unroll
            for (int ni = 0; ni < 3; ++ni)
                b[ni] = *(const bf16x8*)&w2t_l[(size_t)(ncol0 + ni * 16 + lr) * 640 + k0];
            #pragma unroll
            for (int mi = 0; mi < 2; ++mi)
                #pragma unroll
                for (int ni = 0; ni < 3; ++ni)
                    acc[mi][ni] = __builtin_amdgcn_mfma_f32_16x16x32_bf16(
                        a[mi], b[ni], acc[mi][ni], 0, 0, 0);
        }
        #pragma unroll
        for (int ni = 0; ni < 3; ++ni) {
            const int n = ncol0 + ni * 16 + lr;
            if (n < 300) {
                const float gv = g2_l[n];
                const float bv = b2_l[n];
                const float ev = e2_l[n];
                #pragma unroll
                for (int mi = 0; mi < 2; ++mi) {
                    #pragma unroll
                    for (int r = 0; r < 4; ++r) {
                        const int m = mi * 16 + q4 + r;
                        float v = gv * (acc[mi][ni][r] + bv) + ev;
                        if (RELU) v = fmaxf(v, 0.f);
                        h[(size_t)(bm + m) * EMB + n] = v;
                    }
                }
            }
        }
    }
}

// ---------------------------------------------------------------------------
extern "C" void kernel_launch(void* const* d_in, const int* in_sizes, int n_in,
                              void* d_out, int out_size, void* d_ws, size_t ws_size,
                              hipStream_t stream)
{
    const int*   order_p       = (const int*)d_in[0];
    const int*   x_atom        = (const int*)d_in[1];
    const int*   edge_index    = (const int*)d_in[2];
    const int*   edge_attr     = (const int*)d_in[3];
    const float* atom_tab      = (const float*)d_in[4];
    const float* bond_tab_root = (const float*)d_in[5];
    const float* edge_lin_w    = (const float*)d_in[6];
    const float* edge_lin_b    = (const float*)d_in[7];
    const float* bond_tabs     = (const float*)d_in[8];
    const float* eps           = (const float*)d_in[9];
    const float* w1            = (const float*)d_in[10];
    const float* b1            = (const float*)d_in[11];
    const float* bn1g          = (const float*)d_in[12];
    const float* bn1b          = (const float*)d_in[13];
    const float* w2            = (const float*)d_in[14];
    const float* b2            = (const float*)d_in[15];
    const float* bng           = (const float*)d_in[16];
    const float* bnb           = (const float*)d_in[17];

    float* h = (float*)d_out;   // [65536][300] fp32 master activations

    char* ws = (char*)d_ws;
    __bf16* Ahi_g = (__bf16*)ws;                                // 17,825,792 B
    __bf16* Alo_g = (__bf16*)(ws + 17825792);                   // 17,825,792 B
    __bf16* w1t   = (__bf16*)(ws + 83886080);                   // [5][640][320] = 2,048,000 B
    __bf16* w2t   = (__bf16*)(ws + 83886080 + 2048000);         // [5][384][640] = 2,457,600 B
    __bf16* zb    = (__bf16*)(ws + 83886080 + 2048000 + 2457600); // [65536][320] = 41,943,040 B

    prep_w_kernel<<<8800, 256, 0, stream>>>(w1, w2, w1t, w2t);

    adj_kernel<<<NGRAPH, 512, 0, stream>>>(edge_index, edge_attr, bond_tab_root,
                                           edge_lin_w, edge_lin_b, Ahi_g, Alo_g);

    diffuse_mm_kernel<<<NGRAPH, 512, 0, stream>>>(order_p, x_atom, atom_tab,
                                                  Ahi_g, Alo_g, h);

    for (int l = 0; l < NLAYER; ++l) {
        // agg: zb[65536][320] bf16 = (1+eps)h + segsum(relu(h[src]+ee))
        agg_kernel<<<NGRAPH * 2, 1024, 0, stream>>>(
            edge_index, edge_attr, bond_tabs, eps, l, h, zb);

        // fused MLP: h = bn2(relu(bn1(zb@w1)) @ w2), relu except last
        if (l < NLAYER - 1) {
            mlp_kernel<1><<<2048, 512, 0, stream>>>(
                zb, w1t + (size_t)l * 640 * 320, w2t + (size_t)l * 384 * 640, h,
                b1 + l * 600, bn1g + l * 600, bn1b + l * 600,
                b2 + l * 300, bng + l * 300, bnb + l * 300);
        } else {
            mlp_kernel<0><<<2048, 512, 0, stream>>>(
                zb, w1t + (size_t)l * 640 * 320, w2t + (size_t)l * 384 * 640, h,
                b1 + l * 600, bn1g + l * 600, bn1b + l * 600,
                b2 + l * 300, bng + l * 300, bnb + l * 300);
        }
    }
}

// Round 12
// 1096.908 us; speedup vs baseline: 1.5343x; 1.5343x over previous
//
#include <hip/hip_runtime.h>

#define NGRAPH 512
#define NNODE  128
#define NEDGE  512
#define EMB    300
#define NLAYER 5
#define FA     9
#define FB     3
#define VV     64
#define KPAD   136   // padded K stride (bf16 elems) for A / xT tiles

typedef __bf16 bf16x8 __attribute__((ext_vector_type(8)));
typedef __bf16 bf16x4 __attribute__((ext_vector_type(4)));
typedef float  f32x4  __attribute__((ext_vector_type(4)));

__device__ __forceinline__ void gload_lds16(const void* gptr, void* lptr) {
    __builtin_amdgcn_global_load_lds(
        (const __attribute__((address_space(1))) void*)gptr,
        (__attribute__((address_space(3))) void*)lptr, 16, 0, 0);
}

// ---------------------------------------------------------------------------
// Kernel 0: weight prep — transpose w1/w2 to bf16 [N][K] (padded, zeros).
// w1t: [L][640][320]; w2t: [L][320][640].
// ---------------------------------------------------------------------------
__global__ __launch_bounds__(256)
void prep_w_kernel(const float* __restrict__ w1, const float* __restrict__ w2,
                   __bf16* __restrict__ w1t, __bf16* __restrict__ w2t)
{
    const int i = blockIdx.x * 256 + threadIdx.x;
    const int T1 = NLAYER * 640 * 320;
    const int T2 = NLAYER * 320 * 640;
    if (i < T1) {
        const int l = i / (640 * 320);
        const int r = i - l * 640 * 320;
        const int n = r / 320, k = r - n * 320;
        float v = (n < 600 && k < 300) ? w1[((size_t)l * 300 + k) * 600 + n] : 0.f;
        w1t[i] = (__bf16)v;
    } else if (i < T1 + T2) {
        const int j = i - T1;
        const int l = j / (320 * 640);
        const int r = j - l * 320 * 640;
        const int n = r / 640, k = r - n * 640;
        float v = (n < 300 && k < 600) ? w2[((size_t)l * 600 + k) * 300 + n] : 0.f;
        w2t[j] = (__bf16)v;
    }
}

// ---------------------------------------------------------------------------
// Kernel 0b: one-shot CSR precompute. Per graph: packed+sorted edges
// (stable, deterministic order) + node offsets. Reused by all 10 agg blocks
// per layer x 5 layers.
// epk pack: src | dst<<7 | a0<<14 | a1<<20 | a2<<26
// ---------------------------------------------------------------------------
__global__ __launch_bounds__(128)
void csr_kernel(const int* __restrict__ edge_index,
                const int* __restrict__ edge_attr,
                int* __restrict__ epk_sorted,     // [G][512]
                int* __restrict__ off_g)          // [G][129]
{
    __shared__ int epk_s[NEDGE];
    __shared__ int cnt[128];
    __shared__ int off_[129];

    const int tid = threadIdx.x;
    const int g   = blockIdx.x;

    cnt[tid] = 0;
    __syncthreads();
    for (int e = tid; e < NEDGE; e += 128) {
        const int s_ = edge_index[(g * 2 + 0) * NEDGE + e];
        const int d_ = edge_index[(g * 2 + 1) * NEDGE + e];
        const int base = (g * NEDGE + e) * 3;
        epk_s[e] = s_ | (d_ << 7) | (edge_attr[base + 0] << 14)
                 | (edge_attr[base + 1] << 20) | (edge_attr[base + 2] << 26);
        atomicAdd(&cnt[d_], 1);
    }
    __syncthreads();
    if (tid < 64) {
        const int a = cnt[tid];
        const int b = cnt[64 + tid];
        int ia = a;
        #pragma unroll
        for (int o = 1; o < 64; o <<= 1) {
            int t = __shfl_up(ia, o, 64);
            if (tid >= o) ia += t;
        }
        const int totA = __shfl(ia, 63, 64);
        int ib = b;
        #pragma unroll
        for (int o = 1; o < 64; o <<= 1) {
            int t = __shfl_up(ib, o, 64);
            if (tid >= o) ib += t;
        }
        off_[tid]      = ia - a;
        off_[64 + tid] = totA + ib - b;
        if (tid == 63) off_[128] = totA + ib;
    }
    __syncthreads();
    off_g[g * 129 + tid] = off_[tid];
    if (tid == 0) off_g[g * 129 + 128] = off_[128];
    // stable per-dst fill: thread tid owns dst==tid, walks edges in order
    int pos = off_[tid];
    for (int e = 0; e < NEDGE; ++e) {
        const int p = epk_s[e];
        if (((p >> 7) & 127) == tid) epk_sorted[(g << 9) + pos++] = p;
    }
}

// ---------------------------------------------------------------------------
// Kernel 1a: adjacency build (unchanged from round 9)
// ---------------------------------------------------------------------------
__global__ __launch_bounds__(512)
void adj_kernel(const int* __restrict__ edge_index,
                const int* __restrict__ edge_attr,
                const float* __restrict__ bond_tab_root,
                const float* __restrict__ edge_lin_w,
                const float* __restrict__ edge_lin_b,
                __bf16* __restrict__ Ahi_g, __bf16* __restrict__ Alo_g)
{
    __shared__ float A[128 * 129];
    __shared__ float ew_s[NEDGE];
    __shared__ int   es[NEDGE];
    __shared__ float rinv[128];
    __shared__ float cinv[128];

    const int tid = threadIdx.x;
    const int g   = blockIdx.x;
    int* Ai = (int*)A;

    for (int e = tid; e < NEDGE; e += 512) {
        int r = edge_index[(g * 2 + 0) * NEDGE + e];
        int c = edge_index[(g * 2 + 1) * NEDGE + e];
        es[e] = r | (c << 8);
    }
    for (int i = tid; i < 128 * 129; i += 512) Ai[i] = -1;
    __syncthreads();

    {
        const int wave = tid >> 6, lane = tid & 63;
        const float elb = edge_lin_b[0];
        for (int e = wave * 64; e < wave * 64 + 64; ++e) {
            const int base = (g * NEDGE + e) * 3;
            const int a0 = edge_attr[base + 0];
            const int a1 = edge_attr[base + 1];
            const int a2 = edge_attr[base + 2];
            const float* t0 = bond_tab_root + (0 * VV + a0) * EMB;
            const float* t1 = bond_tab_root + (1 * VV + a1) * EMB;
            const float* t2 = bond_tab_root + (2 * VV + a2) * EMB;
            float acc = 0.f;
            for (int d = lane; d < EMB; d += 64)
                acc += (t0[d] + t1[d] + t2[d]) * edge_lin_w[d];
            #pragma unroll
            for (int off = 32; off > 0; off >>= 1) acc += __shfl_xor(acc, off, 64);
            if (lane == 0) ew_s[e] = 1.f / (1.f + expf(-(acc + elb)));
        }
    }
    for (int e = tid; e < NEDGE; e += 512) {
        int r = es[e] & 255, c = es[e] >> 8;
        atomicMax(&Ai[r * 129 + c], e);
        atomicMax(&Ai[c * 129 + r], 512 + e);
    }
    __syncthreads();
    for (int i = tid; i < 128 * 129; i += 512) {
        int p = Ai[i];
        A[i] = (p < 0) ? 0.f : ew_s[p & 511];
    }
    __syncthreads();
    if (tid < 128) A[tid * 129 + tid] += 1.f;
    __syncthreads();
    if (tid < 128) {
        float rs = 0.f, cs = 0.f;
        for (int j = 0; j < 128; ++j) { rs += A[tid * 129 + j]; cs += A[j * 129 + tid]; }
        rinv[tid] = 1.f / sqrtf(rs);
        cinv[tid] = 1.f / sqrtf(cs);
    }
    __syncthreads();
    for (int i = tid; i < 128 * KPAD; i += 512) {
        const int m = i / KPAD, k = i - m * KPAD;
        float v = (k < 128) ? A[m * 129 + k] * cinv[m] * rinv[k] : 0.f;
        __bf16 hi = (__bf16)v;
        Ahi_g[(size_t)g * 128 * KPAD + i] = hi;
        Alo_g[(size_t)g * 128 * KPAD + i] = (__bf16)(v - (float)hi);
    }
}

// ---------------------------------------------------------------------------
// Kernel 1b: diffusion via MFMA with split-bf16.  Output now hb (bf16,
// [65536][320], pad cols zeroed) instead of fp32 h.
// ---------------------------------------------------------------------------
__global__ __launch_bounds__(512)
void diffuse_mm_kernel(const int* __restrict__ order_p,
                       const int* __restrict__ x_atom,
                       const float* __restrict__ atom_tab,
                       const __bf16* __restrict__ Ahi_g,
                       const __bf16* __restrict__ Alo_g,
                       __bf16* __restrict__ hb)
{
    __shared__ __bf16 Ahi[128 * KPAD];
    __shared__ __bf16 Alo[128 * KPAD];
    __shared__ __bf16 xt[4 * 64 * KPAD];
    __shared__ int    xat[128 * FA];

    const int tid  = threadIdx.x;
    const int g    = blockIdx.x;
    const int lane = tid & 63;
    const int wid  = tid >> 6;
    const int wm   = (wid >> 1) * 32;
    const int wn   = (wid & 1) * 32;
    const int lr   = lane & 15;
    const int q4   = (lane >> 4) * 4;
    const int kc   = (lane >> 4) * 8;

    for (int idx = tid; idx < 128 * KPAD / 8; idx += 512) {
        gload_lds16(Ahi_g + (size_t)g * 128 * KPAD + idx * 8, (char*)Ahi + idx * 16);
        gload_lds16(Alo_g + (size_t)g * 128 * KPAD + idx * 8, (char*)Alo + idx * 16);
    }
    for (int i = tid; i < 128 * FA; i += 512) xat[i] = x_atom[g * 128 * FA + i];
    __syncthreads();

    const int   ord    = order_p[0];
    const float yscale = 1.f / (float)(ord + 1);

    for (int cb = 0; cb < 5; ++cb) {
        const int dbase = cb * 64;

        float yacc[2][2][4];
        #pragma unroll
        for (int mi = 0; mi < 2; ++mi) {
            #pragma unroll
            for (int ni = 0; ni < 2; ++ni) {
                const int n_ = wn + ni * 16 + lr;
                const int d  = dbase + n_;
                #pragma unroll
                for (int r = 0; r < 4; ++r) {
                    const int m_ = wm + mi * 16 + q4 + r;
                    float v = 0.f;
                    if (d < EMB) {
                        #pragma unroll
                        for (int f = 0; f < FA; ++f)
                            v += atom_tab[(size_t)((f << 6) + xat[m_ * FA + f]) * EMB + d];
                        v *= 0.8f;
                    }
                    yacc[mi][ni][r] = v;
                    __bf16 hi = (__bf16)v;
                    xt[0 * 64 * KPAD + n_ * KPAD + m_] = hi;
                    xt[1 * 64 * KPAD + n_ * KPAD + m_] = (__bf16)(v - (float)hi);
                }
            }
        }
        __syncthreads();

        int curbuf = 0;
        for (int o = 0; o < ord; ++o) {
            const __bf16* xh = xt + (curbuf * 2 + 0) * 64 * KPAD;
            const __bf16* xl = xt + (curbuf * 2 + 1) * 64 * KPAD;
            f32x4 racc[2][2];
            #pragma unroll
            for (int mi = 0; mi < 2; ++mi)
                #pragma unroll
                for (int ni = 0; ni < 2; ++ni) racc[mi][ni] = (f32x4){0.f, 0.f, 0.f, 0.f};

            #pragma unroll
            for (int ks = 0; ks < 4; ++ks) {
                const int k0 = ks * 32 + kc;
                bf16x8 ah[2], al[2], bh[2], bl[2];
                #pragma unroll
                for (int mi = 0; mi < 2; ++mi) {
                    ah[mi] = *(const bf16x8*)&Ahi[(wm + mi * 16 + lr) * KPAD + k0];
                    al[mi] = *(const bf16x8*)&Alo[(wm + mi * 16 + lr) * KPAD + k0];
                }
                #pragma unroll
                for (int ni = 0; ni < 2; ++ni) {
                    bh[ni] = *(const bf16x8*)&xh[(wn + ni * 16 + lr) * KPAD + k0];
                    bl[ni] = *(const bf16x8*)&xl[(wn + ni * 16 + lr) * KPAD + k0];
                }
                #pragma unroll
                for (int mi = 0; mi < 2; ++mi) {
                    #pragma unroll
                    for (int ni = 0; ni < 2; ++ni) {
                        racc[mi][ni] = __builtin_amdgcn_mfma_f32_16x16x32_bf16(
                            ah[mi], bh[ni], racc[mi][ni], 0, 0, 0);
                        racc[mi][ni] = __builtin_amdgcn_mfma_f32_16x16x32_bf16(
                            ah[mi], bl[ni], racc[mi][ni], 0, 0, 0);
                        racc[mi][ni] = __builtin_amdgcn_mfma_f32_16x16x32_bf16(
                            al[mi], bh[ni], racc[mi][ni], 0, 0, 0);
                    }
                }
            }

            __bf16* nh = xt + ((curbuf ^ 1) * 2 + 0) * 64 * KPAD;
            __bf16* nl = xt + ((curbuf ^ 1) * 2 + 1) * 64 * KPAD;
            #pragma unroll
            for (int mi = 0; mi < 2; ++mi) {
                #pragma unroll
                for (int ni = 0; ni < 2; ++ni) {
                    const int n_ = wn + ni * 16 + lr;
                    const int mbase = wm + mi * 16 + q4;
                    bf16x4 hv, lv;
                    #pragma unroll
                    for (int r = 0; r < 4; ++r) {
                        const float v = racc[mi][ni][r];
                        yacc[mi][ni][r] += v;
                        __bf16 hi = (__bf16)v;
                        hv[r] = hi;
                        lv[r] = (__bf16)(v - (float)hi);
                    }
                    *(bf16x4*)&nh[n_ * KPAD + mbase] = hv;
                    *(bf16x4*)&nl[n_ * KPAD + mbase] = lv;
                }
            }
            __syncthreads();
            curbuf ^= 1;
        }

        // hb write: bf16, stride 320, pad (d>=300) zeroed
        #pragma unroll
        for (int mi = 0; mi < 2; ++mi) {
            #pragma unroll
            for (int ni = 0; ni < 2; ++ni) {
                const int n_ = wn + ni * 16 + lr;
                const int d  = dbase + n_;
                #pragma unroll
                for (int r = 0; r < 4; ++r) {
                    const int m_ = wm + mi * 16 + q4 + r;
                    const float v = (d < EMB) ? yacc[mi][ni][r] * yscale : 0.f;
                    hb[(size_t)(g * 128 + m_) * 320 + d] = (__bf16)v;
                }
            }
        }
    }
}

// ---------------------------------------------------------------------------
// Kernel 2: GIN aggregation, CSR-precomputed gather, 2 blocks/graph.
// hb (bf16) staged into LDS; seed and messages from the same staged values.
// zb = (1+eps)hb + segsum(relu(hb[src]+ee)), written bf16 [65536][320].
// ---------------------------------------------------------------------------
__global__ __launch_bounds__(1024)
void agg_kernel(const __bf16* __restrict__ hb,
                const int* __restrict__ epk_sorted,
                const int* __restrict__ off_g,
                const float* __restrict__ bond_tabs,
                const float* __restrict__ eps_all,
                const int l,
                __bf16* __restrict__ zb)
{
    __shared__ __bf16 hs[128 * 160];   // 40,960 B

    const int tid  = threadIdx.x;
    const int g    = blockIdx.x >> 1;
    const int coff = (blockIdx.x & 1) * 160;
    const int wave = tid >> 6, lane = tid & 63;
    const float epl = 1.f + eps_all[l];
    const float* bt = bond_tabs + (size_t)l * FB * VV * EMB;

    // stage hb chunk (rows 128 x 160 cols), bf16x8 vector loads
    for (int idx = tid; idx < 128 * 20; idx += 1024) {
        const int r = idx / 20, c = idx - r * 20;
        *(bf16x8*)&hs[r * 160 + c * 8] =
            *(const bf16x8*)&hb[(size_t)(g * 128 + r) * 320 + coff + c * 8];
    }
    __syncthreads();

    const int d0 = lane, d1 = lane + 64, d2 = lane + 128;   // d2 valid lane<32
    const bool r0 = (coff + d0) < EMB;
    const bool r1 = (coff + d1) < EMB;
    const bool r2 = (d2 < 160) && ((coff + d2) < EMB);

    const int* offg = off_g + g * 129;
    const int* epkg = epk_sorted + (g << 9);

    for (int n = wave; n < 128; n += 16) {
        float a0 = r0 ? epl * (float)hs[n * 160 + d0] : 0.f;
        float a1 = r1 ? epl * (float)hs[n * 160 + d1] : 0.f;
        float a2 = r2 ? epl * (float)hs[n * 160 + d2] : 0.f;
        const int eBeg = offg[n], eEnd = offg[n + 1];
        for (int ee = eBeg; ee < eEnd; ++ee) {
            const int p   = epkg[ee];
            const int src = p & 127;
            const float* t0 = bt + ((p >> 14) & 63) * EMB + coff;
            const float* t1 = bt + (64  + ((p >> 20) & 63)) * EMB + coff;
            const float* t2 = bt + (128 + ((p >> 26) & 63)) * EMB + coff;
            if (r0) a0 += fmaxf((float)hs[src * 160 + d0] + t0[d0] + t1[d0] + t2[d0], 0.f);
            if (r1) a1 += fmaxf((float)hs[src * 160 + d1] + t0[d1] + t1[d1] + t2[d1], 0.f);
            if (r2) a2 += fmaxf((float)hs[src * 160 + d2] + t0[d2] + t1[d2] + t2[d2], 0.f);
        }
        __bf16* zrow = zb + (size_t)(g * 128 + n) * 320 + coff;
        zrow[d0] = (__bf16)a0;                 // pad cols get 0
        zrow[d1] = (__bf16)a1;
        if (d2 < 160) zrow[d2] = (__bf16)a2;
    }
}

// ---------------------------------------------------------------------------
// Kernel 3: bf16 MFMA GEMM with XCD-chunk swizzle (round-9 exact).
// ---------------------------------------------------------------------------
template <int ABF16, int CBF16, int RELU>
__global__ __launch_bounds__(256)
void gemm_mfma(const void* __restrict__ Av, const int lda, const int Kreal,
               const int nT, const int nBlkN, const __bf16* __restrict__ B,
               void* __restrict__ Cv, const int ldc, const int Nreal,
               const float* __restrict__ bias, const float* __restrict__ gam,
               const float* __restrict__ bet)
{
    __shared__ unsigned short As[128 * 32];
    __shared__ unsigned short Bs[64 * 32];

    const int tid  = threadIdx.x;
    const int nwg  = gridDim.x;
    const int hw   = blockIdx.x;
    const int lg   = (hw & 7) * (nwg >> 3) + (hw >> 3);
    const int bn   = (lg % nBlkN) * 64;
    const int bm   = (lg / nBlkN) * 128;
    const int wid  = tid >> 6;
    const int lane = tid & 63;
    const int wm   = (wid >> 1) * 64;
    const int wn   = (wid & 1) * 32;
    const int lr   = lane & 15;
    const int kc   = (lane >> 4) * 8;
    const int KP   = nT * 32;

    f32x4 acc[4][2];
    #pragma unroll
    for (int mi = 0; mi < 4; ++mi)
        #pragma unroll
        for (int ni = 0; ni < 2; ++ni) acc[mi][ni] = (f32x4){0.f, 0.f, 0.f, 0.f};

    for (int t = 0; t < nT; ++t) {
        const int k0 = t * 32;
        {
            const int n = tid >> 2, k8 = (tid & 3) * 8;
            gload_lds16(B + (size_t)(bn + n) * KP + k0 + k8,
                        (char*)Bs + tid * 16);
        }
        if (ABF16) {
            const __bf16* A = (const __bf16*)Av;
            #pragma unroll
            for (int q = 0; q < 2; ++q) {
                const int idx = q * 256 + tid;
                const int m = idx >> 2, k8 = (idx & 3) * 8;
                gload_lds16(A + (size_t)(bm + m) * lda + k0 + k8,
                            (char*)As + idx * 16);
            }
        } else {
            const float* A = (const float*)Av;
            #pragma unroll
            for (int q = 0; q < 2; ++q) {
                const int idx = q * 256 + tid;
                const int m = idx >> 2;
                const int k = k0 + (idx & 3) * 8;
                const float* src = A + (size_t)(bm + m) * lda + k;
                float v[8];
                if (k + 7 < Kreal) {
                    const float4 u0 = *(const float4*)src;
                    const float4 u1 = *(const float4*)(src + 4);
                    v[0] = u0.x; v[1] = u0.y; v[2] = u0.z; v[3] = u0.w;
                    v[4] = u1.x; v[5] = u1.y; v[6] = u1.z; v[7] = u1.w;
                } else {
                    #pragma unroll
                    for (int j = 0; j < 8; ++j) v[j] = (k + j < Kreal) ? src[j] : 0.f;
                }
                bf16x8 p;
                #pragma unroll
                for (int j = 0; j < 8; ++j) p[j] = (__bf16)v[j];
                *(bf16x8*)&As[idx * 8] = p;
            }
        }
        __syncthreads();

        bf16x8 a[4], bfr[2];
        #pragma unroll
        for (int mi = 0; mi < 4; ++mi)
            a[mi] = *(const bf16x8*)&As[(wm + mi * 16 + lr) * 32 + kc];
        #pragma unroll
        for (int ni = 0; ni < 2; ++ni)
            bfr[ni] = *(const bf16x8*)&Bs[(wn + ni * 16 + lr) * 32 + kc];
        #pragma unroll
        for (int mi = 0; mi < 4; ++mi)
            #pragma unroll
            for (int ni = 0; ni < 2; ++ni)
                acc[mi][ni] = __builtin_amdgcn_mfma_f32_16x16x32_bf16(
                    a[mi], bfr[ni], acc[mi][ni], 0, 0, 0);
        __syncthreads();
    }

    #pragma unroll
    for (int ni = 0; ni < 2; ++ni) {
        const int n = bn + wn + ni * 16 + lr;
        const bool nv = (n < Nreal);
        const float gv = nv ? gam[n]  : 0.f;
        const float bv = nv ? bias[n] : 0.f;
        const float ev = nv ? bet[n]  : 0.f;
        #pragma unroll
        for (int mi = 0; mi < 4; ++mi) {
            #pragma unroll
            for (int r = 0; r < 4; ++r) {
                const size_t m = bm + wm + mi * 16 + (lane >> 4) * 4 + r;
                float v = gv * (acc[mi][ni][r] + bv) + ev;
                if (RELU) v = fmaxf(v, 0.f);
                if (CBF16) {
                    ((__bf16*)Cv)[m * ldc + n] = (__bf16)v;
                } else if (nv) {
                    ((float*)Cv)[m * ldc + n] = v;
                }
            }
        }
    }
}

// ---------------------------------------------------------------------------
extern "C" void kernel_launch(void* const* d_in, const int* in_sizes, int n_in,
                              void* d_out, int out_size, void* d_ws, size_t ws_size,
                              hipStream_t stream)
{
    const int*   order_p       = (const int*)d_in[0];
    const int*   x_atom        = (const int*)d_in[1];
    const int*   edge_index    = (const int*)d_in[2];
    const int*   edge_attr     = (const int*)d_in[3];
    const float* atom_tab      = (const float*)d_in[4];
    const float* bond_tab_root = (const float*)d_in[5];
    const float* edge_lin_w    = (const float*)d_in[6];
    const float* edge_lin_b    = (const float*)d_in[7];
    const float* bond_tabs     = (const float*)d_in[8];
    const float* eps           = (const float*)d_in[9];
    const float* w1            = (const float*)d_in[10];
    const float* b1            = (const float*)d_in[11];
    const float* bn1g          = (const float*)d_in[12];
    const float* bn1b          = (const float*)d_in[13];
    const float* w2            = (const float*)d_in[14];
    const float* b2            = (const float*)d_in[15];
    const float* bng           = (const float*)d_in[16];
    const float* bnb           = (const float*)d_in[17];

    float*  h  = (float*)d_out;    // final fp32 output [65536][300]
    __bf16* hb = (__bf16*)d_out;   // inter-layer trunk bf16 [65536][320] (41.9MB <= 78.6MB)

    char* ws = (char*)d_ws;
    __bf16* Ahi_g = (__bf16*)ws;                                  // 17,825,792 B (inside z1)
    __bf16* Alo_g = (__bf16*)(ws + 17825792);                     // 17,825,792 B (inside z1)
    __bf16* z1    = (__bf16*)ws;                                  // [65536][640] = 83,886,080 B
    __bf16* w1t   = (__bf16*)(ws + 83886080);                     // [5][640][320] = 2,048,000 B
    __bf16* w2t   = (__bf16*)(ws + 83886080 + 2048000);           // [5][320][640] = 2,048,000 B
    __bf16* zb    = (__bf16*)(ws + 83886080 + 4096000);           // [65536][320] = 41,943,040 B
    int*    epk_s = (int*)(ws + 83886080 + 4096000 + 41943040);   // [512][512]  = 1,048,576 B
    int*    off_g = (int*)(ws + 83886080 + 4096000 + 41943040 + 1048576); // [512][129] = 264,192 B

    prep_w_kernel<<<8000, 256, 0, stream>>>(w1, w2, w1t, w2t);

    csr_kernel<<<NGRAPH, 128, 0, stream>>>(edge_index, edge_attr, epk_s, off_g);

    adj_kernel<<<NGRAPH, 512, 0, stream>>>(edge_index, edge_attr, bond_tab_root,
                                           edge_lin_w, edge_lin_b, Ahi_g, Alo_g);

    diffuse_mm_kernel<<<NGRAPH, 512, 0, stream>>>(order_p, x_atom, atom_tab,
                                                  Ahi_g, Alo_g, hb);

    for (int l = 0; l < NLAYER; ++l) {
        // agg: zb = (1+eps)hb + segsum(relu(hb[src]+ee)), bf16
        agg_kernel<<<NGRAPH * 2, 1024, 0, stream>>>(
            hb, epk_s, off_g, bond_tabs, eps, l, zb);

        // gemm1: z1 = relu(bn1(zb @ w1 + b1))
        gemm_mfma<1, 1, 1><<<5120, 256, 0, stream>>>(
            zb, 320, 320, 10, 10, w1t + (size_t)l * 640 * 320,
            z1, 640, 600, b1 + l * 600, bn1g + l * 600, bn1b + l * 600);

        // gemm2: trunk = bn(z1 @ w2 + b2); bf16 hb for l<4, fp32 d_out for last
        if (l < NLAYER - 1) {
            gemm_mfma<1, 1, 1><<<2560, 256, 0, stream>>>(
                z1, 640, 640, 20, 5, w2t + (size_t)l * 320 * 640,
                hb, 320, 300, b2 + l * 300, bng + l * 300, bnb + l * 300);
        } else {
            gemm_mfma<1, 0, 0><<<2560, 256, 0, stream>>>(
                z1, 640, 640, 20, 5, w2t + (size_t)l * 320 * 640,
                h, EMB, 300, b2 + l * 300, bng + l * 300, bnb + l * 300);
        }
    }
}

// Round 13
// 1083.408 us; speedup vs baseline: 1.5534x; 1.0125x over previous
//
#include <hip/hip_runtime.h>

#define NGRAPH 512
#define NNODE  128
#define NEDGE  512
#define EMB    300
#define NLAYER 5
#define FA     9
#define FB     3
#define VV     64
#define KPAD   136   // padded K stride (bf16 elems) for A / xT tiles

typedef __bf16 bf16x8 __attribute__((ext_vector_type(8)));
typedef __bf16 bf16x4 __attribute__((ext_vector_type(4)));
typedef float  f32x4  __attribute__((ext_vector_type(4)));

__device__ __forceinline__ void gload_lds16(const void* gptr, void* lptr) {
    __builtin_amdgcn_global_load_lds(
        (const __attribute__((address_space(1))) void*)gptr,
        (__attribute__((address_space(3))) void*)lptr, 16, 0, 0);
}

// ---------------------------------------------------------------------------
// Kernel 0: weight prep — transpose w1/w2 to bf16 [N][K] (padded, zeros).
// ---------------------------------------------------------------------------
__global__ __launch_bounds__(256)
void prep_w_kernel(const float* __restrict__ w1, const float* __restrict__ w2,
                   __bf16* __restrict__ w1t, __bf16* __restrict__ w2t)
{
    const int i = blockIdx.x * 256 + threadIdx.x;
    const int T1 = NLAYER * 640 * 320;
    const int T2 = NLAYER * 320 * 640;
    if (i < T1) {
        const int l = i / (640 * 320);
        const int r = i - l * 640 * 320;
        const int n = r / 320, k = r - n * 320;
        float v = (n < 600 && k < 300) ? w1[((size_t)l * 300 + k) * 600 + n] : 0.f;
        w1t[i] = (__bf16)v;
    } else if (i < T1 + T2) {
        const int j = i - T1;
        const int l = j / (320 * 640);
        const int r = j - l * 320 * 640;
        const int n = r / 640, k = r - n * 640;
        float v = (n < 300 && k < 600) ? w2[((size_t)l * 600 + k) * 300 + n] : 0.f;
        w2t[j] = (__bf16)v;
    }
}

// ---------------------------------------------------------------------------
// Kernel 0b: one-shot CSR precompute (unchanged from round 12).
// ---------------------------------------------------------------------------
__global__ __launch_bounds__(128)
void csr_kernel(const int* __restrict__ edge_index,
                const int* __restrict__ edge_attr,
                int* __restrict__ epk_sorted,     // [G][512]
                int* __restrict__ off_g)          // [G][129]
{
    __shared__ int epk_s[NEDGE];
    __shared__ int cnt[128];
    __shared__ int off_[129];

    const int tid = threadIdx.x;
    const int g   = blockIdx.x;

    cnt[tid] = 0;
    __syncthreads();
    for (int e = tid; e < NEDGE; e += 128) {
        const int s_ = edge_index[(g * 2 + 0) * NEDGE + e];
        const int d_ = edge_index[(g * 2 + 1) * NEDGE + e];
        const int base = (g * NEDGE + e) * 3;
        epk_s[e] = s_ | (d_ << 7) | (edge_attr[base + 0] << 14)
                 | (edge_attr[base + 1] << 20) | (edge_attr[base + 2] << 26);
        atomicAdd(&cnt[d_], 1);
    }
    __syncthreads();
    if (tid < 64) {
        const int a = cnt[tid];
        const int b = cnt[64 + tid];
        int ia = a;
        #pragma unroll
        for (int o = 1; o < 64; o <<= 1) {
            int t = __shfl_up(ia, o, 64);
            if (tid >= o) ia += t;
        }
        const int totA = __shfl(ia, 63, 64);
        int ib = b;
        #pragma unroll
        for (int o = 1; o < 64; o <<= 1) {
            int t = __shfl_up(ib, o, 64);
            if (tid >= o) ib += t;
        }
        off_[tid]      = ia - a;
        off_[64 + tid] = totA + ib - b;
        if (tid == 63) off_[128] = totA + ib;
    }
    __syncthreads();
    off_g[g * 129 + tid] = off_[tid];
    if (tid == 0) off_g[g * 129 + 128] = off_[128];
    int pos = off_[tid];
    for (int e = 0; e < NEDGE; ++e) {
        const int p = epk_s[e];
        if (((p >> 7) & 127) == tid) epk_sorted[(g << 9) + pos++] = p;
    }
}

// ---------------------------------------------------------------------------
// Kernel 1a: adjacency build (unchanged)
// ---------------------------------------------------------------------------
__global__ __launch_bounds__(512)
void adj_kernel(const int* __restrict__ edge_index,
                const int* __restrict__ edge_attr,
                const float* __restrict__ bond_tab_root,
                const float* __restrict__ edge_lin_w,
                const float* __restrict__ edge_lin_b,
                __bf16* __restrict__ Ahi_g, __bf16* __restrict__ Alo_g)
{
    __shared__ float A[128 * 129];
    __shared__ float ew_s[NEDGE];
    __shared__ int   es[NEDGE];
    __shared__ float rinv[128];
    __shared__ float cinv[128];

    const int tid = threadIdx.x;
    const int g   = blockIdx.x;
    int* Ai = (int*)A;

    for (int e = tid; e < NEDGE; e += 512) {
        int r = edge_index[(g * 2 + 0) * NEDGE + e];
        int c = edge_index[(g * 2 + 1) * NEDGE + e];
        es[e] = r | (c << 8);
    }
    for (int i = tid; i < 128 * 129; i += 512) Ai[i] = -1;
    __syncthreads();

    {
        const int wave = tid >> 6, lane = tid & 63;
        const float elb = edge_lin_b[0];
        for (int e = wave * 64; e < wave * 64 + 64; ++e) {
            const int base = (g * NEDGE + e) * 3;
            const int a0 = edge_attr[base + 0];
            const int a1 = edge_attr[base + 1];
            const int a2 = edge_attr[base + 2];
            const float* t0 = bond_tab_root + (0 * VV + a0) * EMB;
            const float* t1 = bond_tab_root + (1 * VV + a1) * EMB;
            const float* t2 = bond_tab_root + (2 * VV + a2) * EMB;
            float acc = 0.f;
            for (int d = lane; d < EMB; d += 64)
                acc += (t0[d] + t1[d] + t2[d]) * edge_lin_w[d];
            #pragma unroll
            for (int off = 32; off > 0; off >>= 1) acc += __shfl_xor(acc, off, 64);
            if (lane == 0) ew_s[e] = 1.f / (1.f + expf(-(acc + elb)));
        }
    }
    for (int e = tid; e < NEDGE; e += 512) {
        int r = es[e] & 255, c = es[e] >> 8;
        atomicMax(&Ai[r * 129 + c], e);
        atomicMax(&Ai[c * 129 + r], 512 + e);
    }
    __syncthreads();
    for (int i = tid; i < 128 * 129; i += 512) {
        int p = Ai[i];
        A[i] = (p < 0) ? 0.f : ew_s[p & 511];
    }
    __syncthreads();
    if (tid < 128) A[tid * 129 + tid] += 1.f;
    __syncthreads();
    if (tid < 128) {
        float rs = 0.f, cs = 0.f;
        for (int j = 0; j < 128; ++j) { rs += A[tid * 129 + j]; cs += A[j * 129 + tid]; }
        rinv[tid] = 1.f / sqrtf(rs);
        cinv[tid] = 1.f / sqrtf(cs);
    }
    __syncthreads();
    for (int i = tid; i < 128 * KPAD; i += 512) {
        const int m = i / KPAD, k = i - m * KPAD;
        float v = (k < 128) ? A[m * 129 + k] * cinv[m] * rinv[k] : 0.f;
        __bf16 hi = (__bf16)v;
        Ahi_g[(size_t)g * 128 * KPAD + i] = hi;
        Alo_g[(size_t)g * 128 * KPAD + i] = (__bf16)(v - (float)hi);
    }
}

// ---------------------------------------------------------------------------
// Kernel 1b: diffusion via MFMA, split-bf16. NOW 1024 threads (16 waves,
// 4/SIMD): wave grid 4M x 4N, each wave 32 rows x 16 dims (2x1 frags).
// Same math/rounding as round 12; per-thread encode gather chain halved.
// ---------------------------------------------------------------------------
__global__ __launch_bounds__(1024)
void diffuse_mm_kernel(const int* __restrict__ order_p,
                       const int* __restrict__ x_atom,
                       const float* __restrict__ atom_tab,
                       const __bf16* __restrict__ Ahi_g,
                       const __bf16* __restrict__ Alo_g,
                       __bf16* __restrict__ hb)
{
    __shared__ __bf16 Ahi[128 * KPAD];
    __shared__ __bf16 Alo[128 * KPAD];
    __shared__ __bf16 xt[4 * 64 * KPAD];
    __shared__ int    xat[128 * FA];

    const int tid  = threadIdx.x;
    const int g    = blockIdx.x;
    const int lane = tid & 63;
    const int wid  = tid >> 6;            // 0..15
    const int wm   = (wid >> 2) * 32;     // 0,32,64,96
    const int wn   = (wid & 3) * 16;      // 0,16,32,48
    const int lr   = lane & 15;
    const int q4   = (lane >> 4) * 4;
    const int kc   = (lane >> 4) * 8;

    for (int idx = tid; idx < 128 * KPAD / 8; idx += 1024) {
        gload_lds16(Ahi_g + (size_t)g * 128 * KPAD + idx * 8, (char*)Ahi + idx * 16);
        gload_lds16(Alo_g + (size_t)g * 128 * KPAD + idx * 8, (char*)Alo + idx * 16);
    }
    for (int i = tid; i < 128 * FA; i += 1024) xat[i] = x_atom[g * 128 * FA + i];
    __syncthreads();

    const int   ord    = order_p[0];
    const float yscale = 1.f / (float)(ord + 1);
    const int   n_     = wn + lr;         // this thread's dim column (0..63)

    for (int cb = 0; cb < 5; ++cb) {
        const int dbase = cb * 64;
        const int d     = dbase + n_;

        // ---- encode chunk in fp32, split to xT buf0, seed y ----
        float yacc[2][4];
        #pragma unroll
        for (int mi = 0; mi < 2; ++mi) {
            #pragma unroll
            for (int r = 0; r < 4; ++r) {
                const int m_ = wm + mi * 16 + q4 + r;
                float v = 0.f;
                if (d < EMB) {
                    #pragma unroll
                    for (int f = 0; f < FA; ++f)
                        v += atom_tab[(size_t)((f << 6) + xat[m_ * FA + f]) * EMB + d];
                    v *= 0.8f;
                }
                yacc[mi][r] = v;
                __bf16 hi = (__bf16)v;
                xt[0 * 64 * KPAD + n_ * KPAD + m_] = hi;
                xt[1 * 64 * KPAD + n_ * KPAD + m_] = (__bf16)(v - (float)hi);
            }
        }
        __syncthreads();

        int curbuf = 0;
        for (int o = 0; o < ord; ++o) {
            const __bf16* xh = xt + (curbuf * 2 + 0) * 64 * KPAD;
            const __bf16* xl = xt + (curbuf * 2 + 1) * 64 * KPAD;
            f32x4 racc[2];
            racc[0] = (f32x4){0.f, 0.f, 0.f, 0.f};
            racc[1] = (f32x4){0.f, 0.f, 0.f, 0.f};

            #pragma unroll
            for (int ks = 0; ks < 4; ++ks) {
                const int k0 = ks * 32 + kc;
                bf16x8 ah[2], al[2], bh, bl;
                #pragma unroll
                for (int mi = 0; mi < 2; ++mi) {
                    ah[mi] = *(const bf16x8*)&Ahi[(wm + mi * 16 + lr) * KPAD + k0];
                    al[mi] = *(const bf16x8*)&Alo[(wm + mi * 16 + lr) * KPAD + k0];
                }
                bh = *(const bf16x8*)&xh[(wn + lr) * KPAD + k0];
                bl = *(const bf16x8*)&xl[(wn + lr) * KPAD + k0];
                #pragma unroll
                for (int mi = 0; mi < 2; ++mi) {
                    racc[mi] = __builtin_amdgcn_mfma_f32_16x16x32_bf16(
                        ah[mi], bh, racc[mi], 0, 0, 0);
                    racc[mi] = __builtin_amdgcn_mfma_f32_16x16x32_bf16(
                        ah[mi], bl, racc[mi], 0, 0, 0);
                    racc[mi] = __builtin_amdgcn_mfma_f32_16x16x32_bf16(
                        al[mi], bh, racc[mi], 0, 0, 0);
                }
            }

            __bf16* nh = xt + ((curbuf ^ 1) * 2 + 0) * 64 * KPAD;
            __bf16* nl = xt + ((curbuf ^ 1) * 2 + 1) * 64 * KPAD;
            #pragma unroll
            for (int mi = 0; mi < 2; ++mi) {
                const int mbase = wm + mi * 16 + q4;
                bf16x4 hv, lv;
                #pragma unroll
                for (int r = 0; r < 4; ++r) {
                    const float v = racc[mi][r];
                    yacc[mi][r] += v;
                    __bf16 hi = (__bf16)v;
                    hv[r] = hi;
                    lv[r] = (__bf16)(v - (float)hi);
                }
                *(bf16x4*)&nh[n_ * KPAD + mbase] = hv;
                *(bf16x4*)&nl[n_ * KPAD + mbase] = lv;
            }
            __syncthreads();
            curbuf ^= 1;
        }

        // hb write: bf16, stride 320, pad (d>=300) zeroed
        #pragma unroll
        for (int mi = 0; mi < 2; ++mi) {
            #pragma unroll
            for (int r = 0; r < 4; ++r) {
                const int m_ = wm + mi * 16 + q4 + r;
                const float v = (d < EMB) ? yacc[mi][r] * yscale : 0.f;
                hb[(size_t)(g * 128 + m_) * 320 + d] = (__bf16)v;
            }
        }
    }
}

// ---------------------------------------------------------------------------
// Kernel 2: GIN aggregation, CSR-precomputed gather (unchanged from r12).
// ---------------------------------------------------------------------------
__global__ __launch_bounds__(1024)
void agg_kernel(const __bf16* __restrict__ hb,
                const int* __restrict__ epk_sorted,
                const int* __restrict__ off_g,
                const float* __restrict__ bond_tabs,
                const float* __restrict__ eps_all,
                const int l,
                __bf16* __restrict__ zb)
{
    __shared__ __bf16 hs[128 * 160];

    const int tid  = threadIdx.x;
    const int g    = blockIdx.x >> 1;
    const int coff = (blockIdx.x & 1) * 160;
    const int wave = tid >> 6, lane = tid & 63;
    const float epl = 1.f + eps_all[l];
    const float* bt = bond_tabs + (size_t)l * FB * VV * EMB;

    for (int idx = tid; idx < 128 * 20; idx += 1024) {
        const int r = idx / 20, c = idx - r * 20;
        *(bf16x8*)&hs[r * 160 + c * 8] =
            *(const bf16x8*)&hb[(size_t)(g * 128 + r) * 320 + coff + c * 8];
    }
    __syncthreads();

    const int d0 = lane, d1 = lane + 64, d2 = lane + 128;
    const bool r0 = (coff + d0) < EMB;
    const bool r1 = (coff + d1) < EMB;
    const bool r2 = (d2 < 160) && ((coff + d2) < EMB);

    const int* offg = off_g + g * 129;
    const int* epkg = epk_sorted + (g << 9);

    for (int n = wave; n < 128; n += 16) {
        float a0 = r0 ? epl * (float)hs[n * 160 + d0] : 0.f;
        float a1 = r1 ? epl * (float)hs[n * 160 + d1] : 0.f;
        float a2 = r2 ? epl * (float)hs[n * 160 + d2] : 0.f;
        const int eBeg = offg[n], eEnd = offg[n + 1];
        for (int ee = eBeg; ee < eEnd; ++ee) {
            const int p   = epkg[ee];
            const int src = p & 127;
            const float* t0 = bt + ((p >> 14) & 63) * EMB + coff;
            const float* t1 = bt + (64  + ((p >> 20) & 63)) * EMB + coff;
            const float* t2 = bt + (128 + ((p >> 26) & 63)) * EMB + coff;
            if (r0) a0 += fmaxf((float)hs[src * 160 + d0] + t0[d0] + t1[d0] + t2[d0], 0.f);
            if (r1) a1 += fmaxf((float)hs[src * 160 + d1] + t0[d1] + t1[d1] + t2[d1], 0.f);
            if (r2) a2 += fmaxf((float)hs[src * 160 + d2] + t0[d2] + t1[d2] + t2[d2], 0.f);
        }
        __bf16* zrow = zb + (size_t)(g * 128 + n) * 320 + coff;
        zrow[d0] = (__bf16)a0;
        zrow[d1] = (__bf16)a1;
        if (d2 < 160) zrow[d2] = (__bf16)a2;
    }
}

// ---------------------------------------------------------------------------
// Kernel 3: bf16 MFMA GEMM with XCD-chunk swizzle + LDS-STAGED COALESCED
// EPILOGUE. A always bf16 (zero-padded K). C-tile is staged in the (reused)
// As/Bs LDS buffer with padded stride, then streamed as 16B/128B-line
// coalesced stores (16x fewer store instructions than scalar epilogue).
// ---------------------------------------------------------------------------
template <int CBF16, int RELU>
__global__ __launch_bounds__(256)
void gemm_mfma(const __bf16* __restrict__ A, const int lda,
               const int nT, const int nBlkN, const __bf16* __restrict__ B,
               void* __restrict__ Cv, const int ldc, const int Nreal,
               const float* __restrict__ bias, const float* __restrict__ gam,
               const float* __restrict__ bet)
{
    __shared__ __align__(16) char smem_raw[12288];
    unsigned short* As = (unsigned short*)smem_raw;            // 128x32 bf16 = 8 KB
    unsigned short* Bs = (unsigned short*)(smem_raw + 8192);   // 64x32 bf16 = 4 KB

    const int tid  = threadIdx.x;
    const int nwg  = gridDim.x;
    const int hw   = blockIdx.x;
    const int lg   = (hw & 7) * (nwg >> 3) + (hw >> 3);   // XCD-chunk swizzle
    const int bn   = (lg % nBlkN) * 64;
    const int bm   = (lg / nBlkN) * 128;
    const int wid  = tid >> 6;
    const int lane = tid & 63;
    const int wm   = (wid >> 1) * 64;
    const int wn   = (wid & 1) * 32;
    const int lr   = lane & 15;
    const int kc   = (lane >> 4) * 8;
    const int q4   = (lane >> 4) * 4;
    const int KP   = nT * 32;

    f32x4 acc[4][2];
    #pragma unroll
    for (int mi = 0; mi < 4; ++mi)
        #pragma unroll
        for (int ni = 0; ni < 2; ++ni) acc[mi][ni] = (f32x4){0.f, 0.f, 0.f, 0.f};

    for (int t = 0; t < nT; ++t) {
        const int k0 = t * 32;
        {
            const int n = tid >> 2, k8 = (tid & 3) * 8;
            gload_lds16(B + (size_t)(bn + n) * KP + k0 + k8,
                        (char*)Bs + tid * 16);
        }
        #pragma unroll
        for (int q = 0; q < 2; ++q) {
            const int idx = q * 256 + tid;
            const int m = idx >> 2, k8 = (idx & 3) * 8;
            gload_lds16(A + (size_t)(bm + m) * lda + k0 + k8,
                        (char*)As + idx * 16);
        }
        __syncthreads();

        bf16x8 a[4], bfr[2];
        #pragma unroll
        for (int mi = 0; mi < 4; ++mi)
            a[mi] = *(const bf16x8*)&As[(wm + mi * 16 + lr) * 32 + kc];
        #pragma unroll
        for (int ni = 0; ni < 2; ++ni)
            bfr[ni] = *(const bf16x8*)&Bs[(wn + ni * 16 + lr) * 32 + kc];
        #pragma unroll
        for (int mi = 0; mi < 4; ++mi)
            #pragma unroll
            for (int ni = 0; ni < 2; ++ni)
                acc[mi][ni] = __builtin_amdgcn_mfma_f32_16x16x32_bf16(
                    a[mi], bfr[ni], acc[mi][ni], 0, 0, 0);
        __syncthreads();
    }

    // ---- staged coalesced epilogue ----
    float gv[2], bv[2], ev[2];
    #pragma unroll
    for (int ni = 0; ni < 2; ++ni) {
        const int n = bn + wn + ni * 16 + lr;
        const bool nv = (n < Nreal);
        gv[ni] = nv ? gam[n]  : 0.f;
        bv[ni] = nv ? bias[n] : 0.f;
        ev[ni] = nv ? bet[n]  : 0.f;
    }

    if (CBF16) {
        __bf16* Cb = (__bf16*)smem_raw;               // [64][72] padded (9,216 B)
        #pragma unroll
        for (int half = 0; half < 2; ++half) {
            if ((wm >> 6) == half) {
                #pragma unroll
                for (int ni = 0; ni < 2; ++ni) {
                    const int nl = wn + ni * 16 + lr;
                    #pragma unroll
                    for (int mi = 0; mi < 4; ++mi) {
                        #pragma unroll
                        for (int r = 0; r < 4; ++r) {
                            float v = gv[ni] * (acc[mi][ni][r] + bv[ni]) + ev[ni];
                            if (RELU) v = fmaxf(v, 0.f);
                            Cb[(mi * 16 + q4 + r) * 72 + nl] = (__bf16)v;
                        }
                    }
                }
            }
            __syncthreads();
            #pragma unroll
            for (int q = 0; q < 2; ++q) {
                const int idx = q * 256 + tid;
                const int row = idx >> 3, c16 = (idx & 7) * 8;
                const size_t m = (size_t)bm + half * 64 + row;
                *(bf16x8*)&((__bf16*)Cv)[m * ldc + bn + c16] =
                    *(const bf16x8*)&Cb[row * 72 + c16];
            }
            __syncthreads();
        }
    } else {
        float* Cf = (float*)smem_raw;                 // [32][68] padded (8,704 B)
        const int ncols = (Nreal - bn < 64) ? (Nreal - bn) : 64;
        const int nch = ncols >> 2;                   // float4 chunks/row
        #pragma unroll
        for (int mq = 0; mq < 4; ++mq) {
            if ((wm >> 6) == (mq >> 1)) {
                const int mi0 = (mq & 1) * 2;
                #pragma unroll
                for (int ni = 0; ni < 2; ++ni) {
                    const int nl = wn + ni * 16 + lr;
                    #pragma unroll
                    for (int mi2 = 0; mi2 < 2; ++mi2) {
                        const int mi = mi0 + mi2;
                        #pragma unroll
                        for (int r = 0; r < 4; ++r) {
                            float v = gv[ni] * (acc[mi][ni][r] + bv[ni]) + ev[ni];
                            if (RELU) v = fmaxf(v, 0.f);
                            Cf[(mi2 * 16 + q4 + r) * 68 + nl] = v;
                        }
                    }
                }
            }
            __syncthreads();
            for (int idx = tid; idx < 32 * nch; idx += 256) {
                const int row = idx / nch, c4 = (idx - row * nch) * 4;
                const size_t m = (size_t)bm + mq * 32 + row;
                *(float4*)&((float*)Cv)[m * ldc + bn + c4] =
                    *(const float4*)&Cf[row * 68 + c4];
            }
            __syncthreads();
        }
    }
}

// ---------------------------------------------------------------------------
extern "C" void kernel_launch(void* const* d_in, const int* in_sizes, int n_in,
                              void* d_out, int out_size, void* d_ws, size_t ws_size,
                              hipStream_t stream)
{
    const int*   order_p       = (const int*)d_in[0];
    const int*   x_atom        = (const int*)d_in[1];
    const int*   edge_index    = (const int*)d_in[2];
    const int*   edge_attr     = (const int*)d_in[3];
    const float* atom_tab      = (const float*)d_in[4];
    const float* bond_tab_root = (const float*)d_in[5];
    const float* edge_lin_w    = (const float*)d_in[6];
    const float* edge_lin_b    = (const float*)d_in[7];
    const float* bond_tabs     = (const float*)d_in[8];
    const float* eps           = (const float*)d_in[9];
    const float* w1            = (const float*)d_in[10];
    const float* b1            = (const float*)d_in[11];
    const float* bn1g          = (const float*)d_in[12];
    const float* bn1b          = (const float*)d_in[13];
    const float* w2            = (const float*)d_in[14];
    const float* b2            = (const float*)d_in[15];
    const float* bng           = (const float*)d_in[16];
    const float* bnb           = (const float*)d_in[17];

    float*  h  = (float*)d_out;    // final fp32 output [65536][300]
    __bf16* hb = (__bf16*)d_out;   // inter-layer trunk bf16 [65536][320]

    char* ws = (char*)d_ws;
    __bf16* Ahi_g = (__bf16*)ws;                                  // 17,825,792 B (inside z1)
    __bf16* Alo_g = (__bf16*)(ws + 17825792);                     // 17,825,792 B (inside z1)
    __bf16* z1    = (__bf16*)ws;                                  // [65536][640] = 83,886,080 B
    __bf16* w1t   = (__bf16*)(ws + 83886080);                     // [5][640][320]
    __bf16* w2t   = (__bf16*)(ws + 83886080 + 2048000);           // [5][320][640]
    __bf16* zb    = (__bf16*)(ws + 83886080 + 4096000);           // [65536][320]
    int*    epk_s = (int*)(ws + 83886080 + 4096000 + 41943040);   // [512][512]
    int*    off_g = (int*)(ws + 83886080 + 4096000 + 41943040 + 1048576); // [512][129]

    prep_w_kernel<<<8000, 256, 0, stream>>>(w1, w2, w1t, w2t);

    csr_kernel<<<NGRAPH, 128, 0, stream>>>(edge_index, edge_attr, epk_s, off_g);

    adj_kernel<<<NGRAPH, 512, 0, stream>>>(edge_index, edge_attr, bond_tab_root,
                                           edge_lin_w, edge_lin_b, Ahi_g, Alo_g);

    diffuse_mm_kernel<<<NGRAPH, 1024, 0, stream>>>(order_p, x_atom, atom_tab,
                                                   Ahi_g, Alo_g, hb);

    for (int l = 0; l < NLAYER; ++l) {
        agg_kernel<<<NGRAPH * 2, 1024, 0, stream>>>(
            hb, epk_s, off_g, bond_tabs, eps, l, zb);

        // gemm1: z1 = relu(bn1(zb @ w1 + b1))
        gemm_mfma<1, 1><<<5120, 256, 0, stream>>>(
            zb, 320, 10, 10, w1t + (size_t)l * 640 * 320,
            z1, 640, 600, b1 + l * 600, bn1g + l * 600, bn1b + l * 600);

        // gemm2: trunk = bn(z1 @ w2 + b2); bf16 hb for l<4, fp32 d_out for last
        if (l < NLAYER - 1) {
            gemm_mfma<1, 1><<<2560, 256, 0, stream>>>(
                z1, 640, 20, 5, w2t + (size_t)l * 320 * 640,
                hb, 320, 300, b2 + l * 300, bng + l * 300, bnb + l * 300);
        } else {
            gemm_mfma<0, 0><<<2560, 256, 0, stream>>>(
                z1, 640, 20, 5, w2t + (size_t)l * 320 * 640,
                h, EMB, 300, b2 + l * 300, bng + l * 300, bnb + l * 300);
        }
    }
}

// Round 14
// 1057.283 us; speedup vs baseline: 1.5918x; 1.0247x over previous
//
#include <hip/hip_runtime.h>

#define NGRAPH 512
#define NNODE  128
#define NEDGE  512
#define EMB    300
#define NLAYER 5
#define FA     9
#define FB     3
#define VV     64
#define KPAD   136   // padded K stride (bf16 elems) for A / xT tiles

typedef __bf16 bf16x8 __attribute__((ext_vector_type(8)));
typedef __bf16 bf16x4 __attribute__((ext_vector_type(4)));
typedef float  f32x4  __attribute__((ext_vector_type(4)));

__device__ __forceinline__ void gload_lds16(const void* gptr, void* lptr) {
    __builtin_amdgcn_global_load_lds(
        (const __attribute__((address_space(1))) void*)gptr,
        (__attribute__((address_space(3))) void*)lptr, 16, 0, 0);
}

// ---------------------------------------------------------------------------
// Kernel 0: weight prep — transpose w1/w2 to bf16 [N][K] (padded, zeros).
// ---------------------------------------------------------------------------
__global__ __launch_bounds__(256)
void prep_w_kernel(const float* __restrict__ w1, const float* __restrict__ w2,
                   __bf16* __restrict__ w1t, __bf16* __restrict__ w2t)
{
    const int i = blockIdx.x * 256 + threadIdx.x;
    const int T1 = NLAYER * 640 * 320;
    const int T2 = NLAYER * 320 * 640;
    if (i < T1) {
        const int l = i / (640 * 320);
        const int r = i - l * 640 * 320;
        const int n = r / 320, k = r - n * 320;
        float v = (n < 600 && k < 300) ? w1[((size_t)l * 300 + k) * 600 + n] : 0.f;
        w1t[i] = (__bf16)v;
    } else if (i < T1 + T2) {
        const int j = i - T1;
        const int l = j / (320 * 640);
        const int r = j - l * 320 * 640;
        const int n = r / 640, k = r - n * 640;
        float v = (n < 300 && k < 600) ? w2[((size_t)l * 600 + k) * 300 + n] : 0.f;
        w2t[j] = (__bf16)v;
    }
}

// ---------------------------------------------------------------------------
// Kernel 0b: one-shot CSR precompute (unchanged).
// ---------------------------------------------------------------------------
__global__ __launch_bounds__(128)
void csr_kernel(const int* __restrict__ edge_index,
                const int* __restrict__ edge_attr,
                int* __restrict__ epk_sorted,     // [G][512]
                int* __restrict__ off_g)          // [G][129]
{
    __shared__ int epk_s[NEDGE];
    __shared__ int cnt[128];
    __shared__ int off_[129];

    const int tid = threadIdx.x;
    const int g   = blockIdx.x;

    cnt[tid] = 0;
    __syncthreads();
    for (int e = tid; e < NEDGE; e += 128) {
        const int s_ = edge_index[(g * 2 + 0) * NEDGE + e];
        const int d_ = edge_index[(g * 2 + 1) * NEDGE + e];
        const int base = (g * NEDGE + e) * 3;
        epk_s[e] = s_ | (d_ << 7) | (edge_attr[base + 0] << 14)
                 | (edge_attr[base + 1] << 20) | (edge_attr[base + 2] << 26);
        atomicAdd(&cnt[d_], 1);
    }
    __syncthreads();
    if (tid < 64) {
        const int a = cnt[tid];
        const int b = cnt[64 + tid];
        int ia = a;
        #pragma unroll
        for (int o = 1; o < 64; o <<= 1) {
            int t = __shfl_up(ia, o, 64);
            if (tid >= o) ia += t;
        }
        const int totA = __shfl(ia, 63, 64);
        int ib = b;
        #pragma unroll
        for (int o = 1; o < 64; o <<= 1) {
            int t = __shfl_up(ib, o, 64);
            if (tid >= o) ib += t;
        }
        off_[tid]      = ia - a;
        off_[64 + tid] = totA + ib - b;
        if (tid == 63) off_[128] = totA + ib;
    }
    __syncthreads();
    off_g[g * 129 + tid] = off_[tid];
    if (tid == 0) off_g[g * 129 + 128] = off_[128];
    int pos = off_[tid];
    for (int e = 0; e < NEDGE; ++e) {
        const int p = epk_s[e];
        if (((p >> 7) & 127) == tid) epk_sorted[(g << 9) + pos++] = p;
    }
}

// ---------------------------------------------------------------------------
// Kernel 1a: adjacency build. Edge-weight phase now 8-lanes-per-edge
// (64 edges in flight per wave; 3-step subgroup shuffle reduce).
// ---------------------------------------------------------------------------
__global__ __launch_bounds__(512)
void adj_kernel(const int* __restrict__ edge_index,
                const int* __restrict__ edge_attr,
                const float* __restrict__ bond_tab_root,
                const float* __restrict__ edge_lin_w,
                const float* __restrict__ edge_lin_b,
                __bf16* __restrict__ Ahi_g, __bf16* __restrict__ Alo_g)
{
    __shared__ float A[128 * 129];
    __shared__ float ew_s[NEDGE];
    __shared__ int   es[NEDGE];
    __shared__ float rinv[128];
    __shared__ float cinv[128];

    const int tid = threadIdx.x;
    const int g   = blockIdx.x;
    int* Ai = (int*)A;

    for (int e = tid; e < NEDGE; e += 512) {
        int r = edge_index[(g * 2 + 0) * NEDGE + e];
        int c = edge_index[(g * 2 + 1) * NEDGE + e];
        es[e] = r | (c << 8);
    }
    for (int i = tid; i < 128 * 129; i += 512) Ai[i] = -1;
    __syncthreads();

    // edge weights: 8 lanes per edge, 8 edges per wave-iteration
    {
        const int wave = tid >> 6, lane = tid & 63;
        const int sub = lane >> 3, sl = lane & 7;
        const float elb = edge_lin_b[0];
        #pragma unroll 2
        for (int it = 0; it < 8; ++it) {
            const int e = wave * 64 + it * 8 + sub;
            const int base = (g * NEDGE + e) * 3;
            const int a0 = edge_attr[base + 0];
            const int a1 = edge_attr[base + 1];
            const int a2 = edge_attr[base + 2];
            const float* t0 = bond_tab_root + (0 * VV + a0) * EMB;
            const float* t1 = bond_tab_root + (1 * VV + a1) * EMB;
            const float* t2 = bond_tab_root + (2 * VV + a2) * EMB;
            float acc = 0.f;
            for (int d = sl; d < EMB; d += 8)
                acc += (t0[d] + t1[d] + t2[d]) * edge_lin_w[d];
            acc += __shfl_xor(acc, 4, 64);
            acc += __shfl_xor(acc, 2, 64);
            acc += __shfl_xor(acc, 1, 64);
            if (sl == 0) ew_s[e] = 1.f / (1.f + expf(-(acc + elb)));
        }
    }
    for (int e = tid; e < NEDGE; e += 512) {
        int r = es[e] & 255, c = es[e] >> 8;
        atomicMax(&Ai[r * 129 + c], e);
        atomicMax(&Ai[c * 129 + r], 512 + e);
    }
    __syncthreads();
    for (int i = tid; i < 128 * 129; i += 512) {
        int p = Ai[i];
        A[i] = (p < 0) ? 0.f : ew_s[p & 511];
    }
    __syncthreads();
    if (tid < 128) A[tid * 129 + tid] += 1.f;
    __syncthreads();
    if (tid < 128) {
        float rs = 0.f, cs = 0.f;
        for (int j = 0; j < 128; ++j) { rs += A[tid * 129 + j]; cs += A[j * 129 + tid]; }
        rinv[tid] = 1.f / sqrtf(rs);
        cinv[tid] = 1.f / sqrtf(cs);
    }
    __syncthreads();
    for (int i = tid; i < 128 * KPAD; i += 512) {
        const int m = i / KPAD, k = i - m * KPAD;
        float v = (k < 128) ? A[m * 129 + k] * cinv[m] * rinv[k] : 0.f;
        __bf16 hi = (__bf16)v;
        Ahi_g[(size_t)g * 128 * KPAD + i] = hi;
        Alo_g[(size_t)g * 128 * KPAD + i] = (__bf16)(v - (float)hi);
    }
}

// ---------------------------------------------------------------------------
// Kernel 1b: diffusion via MFMA. Split-bf16 on A only (Ahi,Alo); x is
// rounded to bf16 per hop (xlo term dropped — same rounding magnitude as
// the bf16 trunk). 2 MFMA per (ks,mi) instead of 3; xt halves.
// 1024 threads (16 waves), wave grid 4M x 4N.
// ---------------------------------------------------------------------------
__global__ __launch_bounds__(1024)
void diffuse_mm_kernel(const int* __restrict__ order_p,
                       const int* __restrict__ x_atom,
                       const float* __restrict__ atom_tab,
                       const __bf16* __restrict__ Ahi_g,
                       const __bf16* __restrict__ Alo_g,
                       __bf16* __restrict__ hb)
{
    __shared__ __bf16 Ahi[128 * KPAD];        // 34,816 B
    __shared__ __bf16 Alo[128 * KPAD];        // 34,816 B
    __shared__ __bf16 xt[2 * 64 * KPAD];      // 34,816 B (hi only, ping-pong)
    __shared__ int    xat[128 * FA];          // 4,608 B

    const int tid  = threadIdx.x;
    const int g    = blockIdx.x;
    const int lane = tid & 63;
    const int wid  = tid >> 6;            // 0..15
    const int wm   = (wid >> 2) * 32;     // 0,32,64,96
    const int wn   = (wid & 3) * 16;      // 0,16,32,48
    const int lr   = lane & 15;
    const int q4   = (lane >> 4) * 4;
    const int kc   = (lane >> 4) * 8;

    for (int idx = tid; idx < 128 * KPAD / 8; idx += 1024) {
        gload_lds16(Ahi_g + (size_t)g * 128 * KPAD + idx * 8, (char*)Ahi + idx * 16);
        gload_lds16(Alo_g + (size_t)g * 128 * KPAD + idx * 8, (char*)Alo + idx * 16);
    }
    for (int i = tid; i < 128 * FA; i += 1024) xat[i] = x_atom[g * 128 * FA + i];
    __syncthreads();

    const int   ord    = order_p[0];
    const float yscale = 1.f / (float)(ord + 1);
    const int   n_     = wn + lr;         // this thread's dim column (0..63)

    for (int cb = 0; cb < 5; ++cb) {
        const int dbase = cb * 64;
        const int d     = dbase + n_;

        // ---- encode chunk in fp32 -> bf16 xT buf0, seed y ----
        float yacc[2][4];
        #pragma unroll
        for (int mi = 0; mi < 2; ++mi) {
            #pragma unroll
            for (int r = 0; r < 4; ++r) {
                const int m_ = wm + mi * 16 + q4 + r;
                float v = 0.f;
                if (d < EMB) {
                    #pragma unroll
                    for (int f = 0; f < FA; ++f)
                        v += atom_tab[(size_t)((f << 6) + xat[m_ * FA + f]) * EMB + d];
                    v *= 0.8f;
                }
                yacc[mi][r] = v;
                xt[0 * 64 * KPAD + n_ * KPAD + m_] = (__bf16)v;
            }
        }
        __syncthreads();

        int curbuf = 0;
        for (int o = 0; o < ord; ++o) {
            const __bf16* xh = xt + curbuf * 64 * KPAD;
            f32x4 racc[2];
            racc[0] = (f32x4){0.f, 0.f, 0.f, 0.f};
            racc[1] = (f32x4){0.f, 0.f, 0.f, 0.f};

            #pragma unroll
            for (int ks = 0; ks < 4; ++ks) {
                const int k0 = ks * 32 + kc;
                bf16x8 ah[2], al[2], bh;
                #pragma unroll
                for (int mi = 0; mi < 2; ++mi) {
                    ah[mi] = *(const bf16x8*)&Ahi[(wm + mi * 16 + lr) * KPAD + k0];
                    al[mi] = *(const bf16x8*)&Alo[(wm + mi * 16 + lr) * KPAD + k0];
                }
                bh = *(const bf16x8*)&xh[(wn + lr) * KPAD + k0];
                #pragma unroll
                for (int mi = 0; mi < 2; ++mi) {
                    racc[mi] = __builtin_amdgcn_mfma_f32_16x16x32_bf16(
                        ah[mi], bh, racc[mi], 0, 0, 0);
                    racc[mi] = __builtin_amdgcn_mfma_f32_16x16x32_bf16(
                        al[mi], bh, racc[mi], 0, 0, 0);
                }
            }

            __bf16* nh = xt + (curbuf ^ 1) * 64 * KPAD;
            #pragma unroll
            for (int mi = 0; mi < 2; ++mi) {
                const int mbase = wm + mi * 16 + q4;
                bf16x4 hv;
                #pragma unroll
                for (int r = 0; r < 4; ++r) {
                    const float v = racc[mi][r];
                    yacc[mi][r] += v;
                    hv[r] = (__bf16)v;
                }
                *(bf16x4*)&nh[n_ * KPAD + mbase] = hv;
            }
            __syncthreads();
            curbuf ^= 1;
        }

        // hb write: bf16, stride 320, pad (d>=300) zeroed
        #pragma unroll
        for (int mi = 0; mi < 2; ++mi) {
            #pragma unroll
            for (int r = 0; r < 4; ++r) {
                const int m_ = wm + mi * 16 + q4 + r;
                const float v = (d < EMB) ? yacc[mi][r] * yscale : 0.f;
                hb[(size_t)(g * 128 + m_) * 320 + d] = (__bf16)v;
            }
        }
    }
}

// ---------------------------------------------------------------------------
// Kernel 2: GIN aggregation, CSR-precomputed gather (unchanged).
// ---------------------------------------------------------------------------
__global__ __launch_bounds__(1024)
void agg_kernel(const __bf16* __restrict__ hb,
                const int* __restrict__ epk_sorted,
                const int* __restrict__ off_g,
                const float* __restrict__ bond_tabs,
                const float* __restrict__ eps_all,
                const int l,
                __bf16* __restrict__ zb)
{
    __shared__ __bf16 hs[128 * 160];

    const int tid  = threadIdx.x;
    const int g    = blockIdx.x >> 1;
    const int coff = (blockIdx.x & 1) * 160;
    const int wave = tid >> 6, lane = tid & 63;
    const float epl = 1.f + eps_all[l];
    const float* bt = bond_tabs + (size_t)l * FB * VV * EMB;

    for (int idx = tid; idx < 128 * 20; idx += 1024) {
        const int r = idx / 20, c = idx - r * 20;
        *(bf16x8*)&hs[r * 160 + c * 8] =
            *(const bf16x8*)&hb[(size_t)(g * 128 + r) * 320 + coff + c * 8];
    }
    __syncthreads();

    const int d0 = lane, d1 = lane + 64, d2 = lane + 128;
    const bool r0 = (coff + d0) < EMB;
    const bool r1 = (coff + d1) < EMB;
    const bool r2 = (d2 < 160) && ((coff + d2) < EMB);

    const int* offg = off_g + g * 129;
    const int* epkg = epk_sorted + (g << 9);

    for (int n = wave; n < 128; n += 16) {
        float a0 = r0 ? epl * (float)hs[n * 160 + d0] : 0.f;
        float a1 = r1 ? epl * (float)hs[n * 160 + d1] : 0.f;
        float a2 = r2 ? epl * (float)hs[n * 160 + d2] : 0.f;
        const int eBeg = offg[n], eEnd = offg[n + 1];
        for (int ee = eBeg; ee < eEnd; ++ee) {
            const int p   = epkg[ee];
            const int src = p & 127;
            const float* t0 = bt + ((p >> 14) & 63) * EMB + coff;
            const float* t1 = bt + (64  + ((p >> 20) & 63)) * EMB + coff;
            const float* t2 = bt + (128 + ((p >> 26) & 63)) * EMB + coff;
            if (r0) a0 += fmaxf((float)hs[src * 160 + d0] + t0[d0] + t1[d0] + t2[d0], 0.f);
            if (r1) a1 += fmaxf((float)hs[src * 160 + d1] + t0[d1] + t1[d1] + t2[d1], 0.f);
            if (r2) a2 += fmaxf((float)hs[src * 160 + d2] + t0[d2] + t1[d2] + t2[d2], 0.f);
        }
        __bf16* zrow = zb + (size_t)(g * 128 + n) * 320 + coff;
        zrow[d0] = (__bf16)a0;
        zrow[d1] = (__bf16)a1;
        if (d2 < 160) zrow[d2] = (__bf16)a2;
    }
}

// ---------------------------------------------------------------------------
// Kernel 3: bf16 MFMA GEMM with XCD-chunk swizzle + LDS-staged coalesced
// epilogue (unchanged from round 13).
// ---------------------------------------------------------------------------
template <int CBF16, int RELU>
__global__ __launch_bounds__(256)
void gemm_mfma(const __bf16* __restrict__ A, const int lda,
               const int nT, const int nBlkN, const __bf16* __restrict__ B,
               void* __restrict__ Cv, const int ldc, const int Nreal,
               const float* __restrict__ bias, const float* __restrict__ gam,
               const float* __restrict__ bet)
{
    __shared__ __align__(16) char smem_raw[12288];
    unsigned short* As = (unsigned short*)smem_raw;            // 128x32 bf16 = 8 KB
    unsigned short* Bs = (unsigned short*)(smem_raw + 8192);   // 64x32 bf16 = 4 KB

    const int tid  = threadIdx.x;
    const int nwg  = gridDim.x;
    const int hw   = blockIdx.x;
    const int lg   = (hw & 7) * (nwg >> 3) + (hw >> 3);   // XCD-chunk swizzle
    const int bn   = (lg % nBlkN) * 64;
    const int bm   = (lg / nBlkN) * 128;
    const int wid  = tid >> 6;
    const int lane = tid & 63;
    const int wm   = (wid >> 1) * 64;
    const int wn   = (wid & 1) * 32;
    const int lr   = lane & 15;
    const int kc   = (lane >> 4) * 8;
    const int q4   = (lane >> 4) * 4;
    const int KP   = nT * 32;

    f32x4 acc[4][2];
    #pragma unroll
    for (int mi = 0; mi < 4; ++mi)
        #pragma unroll
        for (int ni = 0; ni < 2; ++ni) acc[mi][ni] = (f32x4){0.f, 0.f, 0.f, 0.f};

    for (int t = 0; t < nT; ++t) {
        const int k0 = t * 32;
        {
            const int n = tid >> 2, k8 = (tid & 3) * 8;
            gload_lds16(B + (size_t)(bn + n) * KP + k0 + k8,
                        (char*)Bs + tid * 16);
        }
        #pragma unroll
        for (int q = 0; q < 2; ++q) {
            const int idx = q * 256 + tid;
            const int m = idx >> 2, k8 = (idx & 3) * 8;
            gload_lds16(A + (size_t)(bm + m) * lda + k0 + k8,
                        (char*)As + idx * 16);
        }
        __syncthreads();

        bf16x8 a[4], bfr[2];
        #pragma unroll
        for (int mi = 0; mi < 4; ++mi)
            a[mi] = *(const bf16x8*)&As[(wm + mi * 16 + lr) * 32 + kc];
        #pragma unroll
        for (int ni = 0; ni < 2; ++ni)
            bfr[ni] = *(const bf16x8*)&Bs[(wn + ni * 16 + lr) * 32 + kc];
        #pragma unroll
        for (int mi = 0; mi < 4; ++mi)
            #pragma unroll
            for (int ni = 0; ni < 2; ++ni)
                acc[mi][ni] = __builtin_amdgcn_mfma_f32_16x16x32_bf16(
                    a[mi], bfr[ni], acc[mi][ni], 0, 0, 0);
        __syncthreads();
    }

    // ---- staged coalesced epilogue ----
    float gv[2], bv[2], ev[2];
    #pragma unroll
    for (int ni = 0; ni < 2; ++ni) {
        const int n = bn + wn + ni * 16 + lr;
        const bool nv = (n < Nreal);
        gv[ni] = nv ? gam[n]  : 0.f;
        bv[ni] = nv ? bias[n] : 0.f;
        ev[ni] = nv ? bet[n]  : 0.f;
    }

    if (CBF16) {
        __bf16* Cb = (__bf16*)smem_raw;               // [64][72] padded
        #pragma unroll
        for (int half = 0; half < 2; ++half) {
            if ((wm >> 6) == half) {
                #pragma unroll
                for (int ni = 0; ni < 2; ++ni) {
                    const int nl = wn + ni * 16 + lr;
                    #pragma unroll
                    for (int mi = 0; mi < 4; ++mi) {
                        #pragma unroll
                        for (int r = 0; r < 4; ++r) {
                            float v = gv[ni] * (acc[mi][ni][r] + bv[ni]) + ev[ni];
                            if (RELU) v = fmaxf(v, 0.f);
                            Cb[(mi * 16 + q4 + r) * 72 + nl] = (__bf16)v;
                        }
                    }
                }
            }
            __syncthreads();
            #pragma unroll
            for (int q = 0; q < 2; ++q) {
                const int idx = q * 256 + tid;
                const int row = idx >> 3, c16 = (idx & 7) * 8;
                const size_t m = (size_t)bm + half * 64 + row;
                *(bf16x8*)&((__bf16*)Cv)[m * ldc + bn + c16] =
                    *(const bf16x8*)&Cb[row * 72 + c16];
            }
            __syncthreads();
        }
    } else {
        float* Cf = (float*)smem_raw;                 // [32][68] padded
        const int ncols = (Nreal - bn < 64) ? (Nreal - bn) : 64;
        const int nch = ncols >> 2;
        #pragma unroll
        for (int mq = 0; mq < 4; ++mq) {
            if ((wm >> 6) == (mq >> 1)) {
                const int mi0 = (mq & 1) * 2;
                #pragma unroll
                for (int ni = 0; ni < 2; ++ni) {
                    const int nl = wn + ni * 16 + lr;
                    #pragma unroll
                    for (int mi2 = 0; mi2 < 2; ++mi2) {
                        const int mi = mi0 + mi2;
                        #pragma unroll
                        for (int r = 0; r < 4; ++r) {
                            float v = gv[ni] * (acc[mi][ni][r] + bv[ni]) + ev[ni];
                            if (RELU) v = fmaxf(v, 0.f);
                            Cf[(mi2 * 16 + q4 + r) * 68 + nl] = v;
                        }
                    }
                }
            }
            __syncthreads();
            for (int idx = tid; idx < 32 * nch; idx += 256) {
                const int row = idx / nch, c4 = (idx - row * nch) * 4;
                const size_t m = (size_t)bm + mq * 32 + row;
                *(float4*)&((float*)Cv)[m * ldc + bn + c4] =
                    *(const float4*)&Cf[row * 68 + c4];
            }
            __syncthreads();
        }
    }
}

// ---------------------------------------------------------------------------
extern "C" void kernel_launch(void* const* d_in, const int* in_sizes, int n_in,
                              void* d_out, int out_size, void* d_ws, size_t ws_size,
                              hipStream_t stream)
{
    const int*   order_p       = (const int*)d_in[0];
    const int*   x_atom        = (const int*)d_in[1];
    const int*   edge_index    = (const int*)d_in[2];
    const int*   edge_attr     = (const int*)d_in[3];
    const float* atom_tab      = (const float*)d_in[4];
    const float* bond_tab_root = (const float*)d_in[5];
    const float* edge_lin_w    = (const float*)d_in[6];
    const float* edge_lin_b    = (const float*)d_in[7];
    const float* bond_tabs     = (const float*)d_in[8];
    const float* eps           = (const float*)d_in[9];
    const float* w1            = (const float*)d_in[10];
    const float* b1            = (const float*)d_in[11];
    const float* bn1g          = (const float*)d_in[12];
    const float* bn1b          = (const float*)d_in[13];
    const float* w2            = (const float*)d_in[14];
    const float* b2            = (const float*)d_in[15];
    const float* bng           = (const float*)d_in[16];
    const float* bnb           = (const float*)d_in[17];

    float*  h  = (float*)d_out;    // final fp32 output [65536][300]
    __bf16* hb = (__bf16*)d_out;   // inter-layer trunk bf16 [65536][320]

    char* ws = (char*)d_ws;
    __bf16* Ahi_g = (__bf16*)ws;                                  // (inside z1)
    __bf16* Alo_g = (__bf16*)(ws + 17825792);                     // (inside z1)
    __bf16* z1    = (__bf16*)ws;                                  // [65536][640]
    __bf16* w1t   = (__bf16*)(ws + 83886080);                     // [5][640][320]
    __bf16* w2t   = (__bf16*)(ws + 83886080 + 2048000);           // [5][320][640]
    __bf16* zb    = (__bf16*)(ws + 83886080 + 4096000);           // [65536][320]
    int*    epk_s = (int*)(ws + 83886080 + 4096000 + 41943040);   // [512][512]
    int*    off_g = (int*)(ws + 83886080 + 4096000 + 41943040 + 1048576); // [512][129]

    prep_w_kernel<<<8000, 256, 0, stream>>>(w1, w2, w1t, w2t);

    csr_kernel<<<NGRAPH, 128, 0, stream>>>(edge_index, edge_attr, epk_s, off_g);

    adj_kernel<<<NGRAPH, 512, 0, stream>>>(edge_index, edge_attr, bond_tab_root,
                                           edge_lin_w, edge_lin_b, Ahi_g, Alo_g);

    diffuse_mm_kernel<<<NGRAPH, 1024, 0, stream>>>(order_p, x_atom, atom_tab,
                                                   Ahi_g, Alo_g, hb);

    for (int l = 0; l < NLAYER; ++l) {
        agg_kernel<<<NGRAPH * 2, 1024, 0, stream>>>(
            hb, epk_s, off_g, bond_tabs, eps, l, zb);

        // gemm1: z1 = relu(bn1(zb @ w1 + b1))
        gemm_mfma<1, 1><<<5120, 256, 0, stream>>>(
            zb, 320, 10, 10, w1t + (size_t)l * 640 * 320,
            z1, 640, 600, b1 + l * 600, bn1g + l * 600, bn1b + l * 600);

        // gemm2: trunk = bn(z1 @ w2 + b2); bf16 hb for l<4, fp32 d_out for last
        if (l < NLAYER - 1) {
            gemm_mfma<1, 1><<<2560, 256, 0, stream>>>(
                z1, 640, 20, 5, w2t + (size_t)l * 320 * 640,
                hb, 320, 300, b2 + l * 300, bng + l * 300, bnb + l * 300);
        } else {
            gemm_mfma<0, 0><<<2560, 256, 0, stream>>>(
                z1, 640, 20, 5, w2t + (size_t)l * 320 * 640,
                h, EMB, 300, b2 + l * 300, bng + l * 300, bnb + l * 300);
        }
    }
}